// Round 8
// baseline (800.386 us; speedup 1.0000x reference)
//
#include <hip/hip_runtime.h>
#include <hip/hip_bf16.h>
#include <math.h>

// ---- problem constants ----
#define D_MODEL 2048
#define SEQ     2048
#define BATCH   2
#define NHEAD   16
#define DK      128
#define DFF     8192
#define MROWS   (BATCH*SEQ)   // 4096 rows

typedef short short8 __attribute__((ext_vector_type(8)));   // 8 bf16 in 4 VGPRs
typedef float f32x4  __attribute__((ext_vector_type(4)));

__device__ __forceinline__ short f2bf(float f) {
  union { __hip_bfloat16 b; short s; } u;
  u.b = __float2bfloat16(f);
  return u.s;
}

#define MF(a, b, c) __builtin_amdgcn_mfma_f32_16x16x32_bf16(a, b, c, 0, 0, 0)
// wave-uniform LDS base via m0, per-lane global addr, 16B/lane direct-to-LDS
#define STG(gptr, ldsbyte) { \
    unsigned _m0v = (unsigned)__builtin_amdgcn_readfirstlane((int)(ldsbyte)); \
    asm volatile("s_mov_b32 m0, %1\n\tglobal_load_lds_dwordx4 %0, off" \
                 :: "v"(gptr), "s"(_m0v) : "memory"); }

// ---------------- RMSNorm: fp32 in -> bf16 out ----------------
__global__ __launch_bounds__(256) void rmsnorm_k(const float* __restrict__ x,
                                                 const float* __restrict__ g,
                                                 short* __restrict__ o) {
  const int row = blockIdx.x;
  const int t = threadIdx.x;
  const float4* xr = (const float4*)(x + (size_t)row * D_MODEL);
  const float4* gr = (const float4*)g;
  float4 v0 = xr[2*t], v1 = xr[2*t+1];
  float s = v0.x*v0.x + v0.y*v0.y + v0.z*v0.z + v0.w*v0.w
          + v1.x*v1.x + v1.y*v1.y + v1.z*v1.z + v1.w*v1.w;
  #pragma unroll
  for (int off = 1; off < 64; off <<= 1) s += __shfl_xor(s, off);
  __shared__ float red[4];
  if ((t & 63) == 0) red[t >> 6] = s;
  __syncthreads();
  float tot = red[0] + red[1] + red[2] + red[3];
  float inv = rsqrtf(tot * (1.0f / D_MODEL) + 1e-5f);
  float4 g0 = gr[2*t], g1v = gr[2*t+1];
  short8 ov;
  ov[0] = f2bf(v0.x * inv * g0.x);
  ov[1] = f2bf(v0.y * inv * g0.y);
  ov[2] = f2bf(v0.z * inv * g0.z);
  ov[3] = f2bf(v0.w * inv * g0.w);
  ov[4] = f2bf(v1.x * inv * g1v.x);
  ov[5] = f2bf(v1.y * inv * g1v.y);
  ov[6] = f2bf(v1.z * inv * g1v.z);
  ov[7] = f2bf(v1.w * inv * g1v.w);
  *((short8*)(o + (size_t)row * D_MODEL) + t) = ov;
}

// ---------------- fp32 -> bf16 convert (weights, one-time) ----------------
__global__ __launch_bounds__(256) void f2b_k(const float* __restrict__ src,
                                             short* __restrict__ dst, int n8) {
  int i = blockIdx.x * 256 + threadIdx.x;
  if (i >= n8) return;
  const float4* s4 = (const float4*)src + 2 * (size_t)i;
  float4 a = s4[0], b = s4[1];
  short8 o = { f2bf(a.x), f2bf(a.y), f2bf(a.z), f2bf(a.w),
               f2bf(b.x), f2bf(b.y), f2bf(b.z), f2bf(b.w) };
  *((short8*)dst + i) = o;
}

// ---------------- split-K combine: o = p0 + p1 + r (fp32) ----------------
__global__ __launch_bounds__(256) void combine_k(const float* p0, const float* p1,
                                                 const float* r, float* o, int n4) {
  int i = blockIdx.x * 256 + threadIdx.x;
  if (i >= n4) return;
  const float4 a = ((const float4*)p0)[i];
  const float4 b = ((const float4*)p1)[i];
  const float4 c = ((const float4*)r)[i];
  float4 d;
  d.x = a.x + b.x + c.x; d.y = a.y + b.y + c.y;
  d.z = a.z + b.z + c.z; d.w = a.w + b.w + c.w;
  ((float4*)o)[i] = d;
}

// ======== 256x256 FIFO counted-vmcnt GEMM (BK=32, 4-slot, never drains) ========
// C[M,N] = A[M,K](bf16) * B[N,K](bf16)^T. 512 thr = 8 waves (2M x 4N), wave 128x64.
// LDS: As/Bs [4 slots][256x32] = 128 KB, LINEAR (row = 64 B -> uniform 2-way bank
// aliasing = free, no swizzle needed; gload_lds dest trivially linear).
// Per K-tile (32): stage tile T+3 (4 loads/thread, strict FIFO), 32 MFMA/wave,
// boundary = s_waitcnt vmcnt(8) lgkmcnt(0); s_barrier.  vmcnt(8) retires exactly
// tile T+1 (oldest 4 loads) while T+2/T+3 (8 loads) stay in flight -> pipeline
// never drains; every waited-on load was issued ~2 tile-times earlier.
// lgkmcnt(0) before the barrier closes the WAR window on slot reuse (4-tile cycle).
// EPI: 0 bf16; 1 GELU bf16; 2 +resid fp32; 3 plain fp32. SPLIT: split-K x2.
template<int EPI, int SPLIT>
__global__ __launch_bounds__(512, 2) void gemm256(const short* __restrict__ A,
                                                  const short* __restrict__ Bp,
                                                  void* Cv,
                                                  const float* __restrict__ resid,
                                                  int M, int N, int K,
                                                  int lda, int ldb, int nbx) {
  __shared__ __align__(16) short As[4][256 * 32];   // 64 KB
  __shared__ __align__(16) short Bs[4][256 * 32];   // 64 KB
  const int nk = K >> 5;                            // BK=32
  const int cpx = gridDim.x >> 3;
  const int lin = (blockIdx.x & 7) * cpx + (blockIdx.x >> 3);
  const int bx = lin % nbx;
  int row2 = lin / nbx, by, ks = 0;
  if (SPLIT) { ks = row2 & 1; by = row2 >> 1; } else { by = row2; }
  const int m0 = bx * 256, n0 = by * 256;
  if (SPLIT) { A += (size_t)ks * K; Bp += (size_t)ks * K; }

  const int t = threadIdx.x, w = t >> 6, lane = t & 63, lr = lane & 15, lg = lane >> 4;
  const int wm = w >> 2, wn = w & 3;
  const unsigned aByte = (unsigned)(size_t)(const __attribute__((address_space(3))) short*)&As[0][0];
  const unsigned bByte = (unsigned)(size_t)(const __attribute__((address_space(3))) short*)&Bs[0][0];
  const unsigned wOff = (unsigned)(w * 1024);

  // staging: thread t -> rows r, r+128; 16B col-chunk (t&3) of the 32-col tile
  const int r = t >> 2, c8s = (t & 3) * 8;
  const short* pA = A  + (size_t)(m0 + r) * lda + c8s;
  const short* pB = Bp + (size_t)(n0 + r) * ldb + c8s;
  const size_t l128A = (size_t)128 * lda, l128B = (size_t)128 * ldb;

  // FIFO stage of one K-tile into slot s (4 loads, strict program order)
#define STAGE(tt, s) { \
    const short* a_ = pA + (size_t)(tt) * 32; \
    STG(a_, aByte + (unsigned)(s) * 16384u + wOff); \
    STG(a_ + l128A, aByte + (unsigned)(s) * 16384u + 8192u + wOff); \
    const short* b_ = pB + (size_t)(tt) * 32; \
    STG(b_, bByte + (unsigned)(s) * 16384u + wOff); \
    STG(b_ + l128B, bByte + (unsigned)(s) * 16384u + 8192u + wOff); }

  f32x4 acc[8][4];
  const f32x4 z4 = {0.f, 0.f, 0.f, 0.f};
  #pragma unroll
  for (int m = 0; m < 8; ++m)
    #pragma unroll
    for (int n = 0; n < 4; ++n) acc[m][n] = z4;

  // one K-tile of compute from slot s (12 ds_read_b128, 32 MFMA)
#define COMPUTE(s) { \
    short8 bf_[4], af_[8]; \
    _Pragma("unroll") \
    for (int n = 0; n < 4; ++n) { \
      int br = wn * 64 + n * 16 + lr; \
      bf_[n] = *(const short8*)&Bs[s][br * 32 + lg * 8]; \
    } \
    _Pragma("unroll") \
    for (int m = 0; m < 8; ++m) { \
      int ar = wm * 128 + m * 16 + lr; \
      af_[m] = *(const short8*)&As[s][ar * 32 + lg * 8]; \
    } \
    _Pragma("unroll") \
    for (int m = 0; m < 8; ++m) \
      _Pragma("unroll") \
      for (int n = 0; n < 4; ++n) acc[m][n] = MF(af_[m], bf_[n], acc[m][n]); }

  // ---- prologue: stage tiles 0,1,2 (12 loads); wait tile0 (vmcnt 8) ----
  STAGE(0, 0); STAGE(1, 1); STAGE(2, 2);
  asm volatile("s_waitcnt vmcnt(8)" ::: "memory");
  __builtin_amdgcn_s_barrier();

  // ---- steady loop: invariant at entry of body(T): {T+1,T+2} in flight (8) ----
  for (int T = 0; T < nk - 3; ++T) {
    STAGE(T + 3, (T + 3) & 3);          // -> 12 in flight
    COMPUTE(T & 3);
    asm volatile("s_waitcnt vmcnt(8) lgkmcnt(0)" ::: "memory");  // T+1 landed
    __builtin_amdgcn_s_barrier();
  }
  // ---- tail: T = nk-3, nk-2, nk-1 (no more staging) ----
  COMPUTE((nk - 3) & 3);
  asm volatile("s_waitcnt vmcnt(4) lgkmcnt(0)" ::: "memory");
  __builtin_amdgcn_s_barrier();
  COMPUTE((nk - 2) & 3);
  asm volatile("s_waitcnt vmcnt(0) lgkmcnt(0)" ::: "memory");
  __builtin_amdgcn_s_barrier();
  COMPUTE((nk - 1) & 3);
#undef STAGE
#undef COMPUTE

  // ---- epilogue ----
  float* Cf = (float*)Cv;
  if (SPLIT) Cf += (size_t)ks * ((size_t)M * N);
  #pragma unroll
  for (int m = 0; m < 8; ++m)
    #pragma unroll
    for (int n = 0; n < 4; ++n)
      #pragma unroll
      for (int rr = 0; rr < 4; ++rr) {
        int row = m0 + wm * 128 + m * 16 + lg * 4 + rr;
        int col = n0 + wn * 64 + n * 16 + lr;
        size_t idx = (size_t)row * N + col;
        float vv = acc[m][n][rr];
        if (EPI == 0) {
          ((short*)Cv)[idx] = f2bf(vv);
        } else if (EPI == 1) {
          float gl = 0.5f * vv * (1.0f + erff(vv * 0.70710678118654752f));
          ((short*)Cv)[idx] = f2bf(gl);
        } else if (EPI == 2) {
          ((float*)Cv)[idx] = vv + resid[idx];
        } else {
          Cf[idx] = vv;
        }
      }
}

// ---------------- V transpose: qkv[.., v cols] -> vt[b][h][d][s] ----------------
__global__ __launch_bounds__(256) void vtrans(const short* __restrict__ QKV,
                                              short* __restrict__ VT) {
  const int st = blockIdx.x;   // s tile of 64
  const int bh = blockIdx.y;
  const int b = bh >> 4, h = bh & 15;
  const int t = threadIdx.x;
  __shared__ __align__(16) short T[64 * 128];
  const short* Vsrc = QKV + ((size_t)b * SEQ) * 6144 + 2 * D_MODEL + h * DK;
  {
    int r = t >> 4, c = (t & 15) * 8;
    #pragma unroll
    for (int i = 0; i < 4; ++i) {
      int rr = r + 16 * i;
      uint4 vv = *(const uint4*)(Vsrc + (size_t)(st * 64 + rr) * 6144 + c);
      *(uint4*)&T[rr * 128 + (c ^ (((rr >> 3) & 7) << 3))] = vv;
    }
  }
  __syncthreads();
  short* dst = VT + ((size_t)bh * DK) * SEQ + st * 64;
  {
    int c2 = (t & 7) * 8;
    #pragma unroll
    for (int i = 0; i < 4; ++i) {
      int d = (t >> 3) + 32 * i;
      short8 ov;
      #pragma unroll
      for (int j = 0; j < 8; ++j)
        ov[j] = T[(c2 + j) * 128 + (d ^ ((((c2 + j) >> 3) & 7) << 3))];
      *(short8*)(dst + (size_t)d * SEQ + c2) = ov;
    }
  }
}

// ---------------- Flash attention v3 (round-4 verified) ----------------
__global__ __launch_bounds__(512, 2) void attn3(const short* __restrict__ QKV,
                                                const short* __restrict__ VT,
                                                short* __restrict__ O) {
  const float SC = 0.12751743f;   // (1/sqrt(128)) * log2(e)
  const int a = blockIdx.x, bh = blockIdx.y;
  const int b = bh >> 4, h = bh & 15;
  const int t = threadIdx.x, w = t >> 6, lane = t & 63, lr = lane & 15, lg = lane >> 4;
  const short* Qp = QKV + ((size_t)b * SEQ) * 6144 + h * DK;
  const short* Kp = Qp + D_MODEL;
  const short* Vp = VT + ((size_t)bh * DK) * SEQ;   // [d][s]
  __shared__ __align__(16) short Ks[2][64 * 128];
  __shared__ __align__(16) short Vs[2][128 * 64];
  __shared__ __align__(16) short Ps[8][16][72];

  const int krr = t >> 4, kcc = (t & 15) * 8;
  const int vdd = t >> 3, vcc = (t & 7) * 8;
  const f32x4 z4 = {0.f, 0.f, 0.f, 0.f};

  for (int sub = 0; sub < 2; ++sub) {
    const int ts = sub ? (15 - a) : a;
    const int nt = 2 * ts + 2;
    const int qrow0 = ts * 128 + w * 16;

    short8 qf[4];
    #pragma unroll
    for (int ki = 0; ki < 4; ++ki)
      qf[ki] = *(const short8*)(Qp + (size_t)(qrow0 + lr) * 6144 + ki * 32 + lg * 8);

    f32x4 acc[8];
    #pragma unroll
    for (int nd = 0; nd < 8; ++nd) acc[nd] = z4;
    float mrow[4], lsum[4];
    #pragma unroll
    for (int r = 0; r < 4; ++r) { mrow[r] = -INFINITY; lsum[r] = 0.f; }

    uint4 krg[2], vrg[2];
    #pragma unroll
    for (int i = 0; i < 2; ++i) {
      krg[i] = *(const uint4*)(Kp + (size_t)(krr + 32 * i) * 6144 + kcc);
      vrg[i] = *(const uint4*)(Vp + (size_t)(vdd + 64 * i) * SEQ + vcc);
    }
    __syncthreads();
    #pragma unroll
    for (int i = 0; i < 2; ++i) {
      int r = krr + 32 * i;
      *(uint4*)&Ks[0][(r * 128 + kcc) ^ ((r & 7) << 3)] = krg[i];
      int d = vdd + 64 * i;
      *(uint4*)&Vs[0][(d * 64 + vcc) ^ ((d & 7) << 3)] = vrg[i];
    }
    __syncthreads();

    int cur = 0;
    for (int tt = 0; tt < nt; ++tt) {
      const bool pre = (tt + 1 < nt);
      if (pre) {
        #pragma unroll
        for (int i = 0; i < 2; ++i) {
          krg[i] = *(const uint4*)(Kp + (size_t)((tt + 1) * 64 + krr + 32 * i) * 6144 + kcc);
          vrg[i] = *(const uint4*)(Vp + (size_t)(vdd + 64 * i) * SEQ + (tt + 1) * 64 + vcc);
        }
      }

      f32x4 sf[4] = {z4, z4, z4, z4};
      #pragma unroll
      for (int ki = 0; ki < 4; ++ki) {
        #pragma unroll
        for (int nk = 0; nk < 4; ++nk) {
          int rr = nk * 16 + lr;
          short8 kf = *(const short8*)&Ks[cur][(rr * 128 + ki * 32 + lg * 8) ^ ((rr & 7) << 3)];
          sf[nk] = MF(qf[ki], kf, sf[nk]);
        }
      }

      const bool diag = (tt * 64 + 63 > qrow0);
      #pragma unroll
      for (int r = 0; r < 4; ++r) {
        int qg = qrow0 + lg * 4 + r;
        float s0 = sf[0][r] * SC, s1 = sf[1][r] * SC, s2 = sf[2][r] * SC, s3 = sf[3][r] * SC;
        if (diag) {
          int c0 = tt * 64 + lr;
          s0 = (c0      <= qg) ? s0 : -3.0e38f;
          s1 = (c0 + 16 <= qg) ? s1 : -3.0e38f;
          s2 = (c0 + 32 <= qg) ? s2 : -3.0e38f;
          s3 = (c0 + 48 <= qg) ? s3 : -3.0e38f;
        }
        float mx = fmaxf(fmaxf(s0, s1), fmaxf(s2, s3));
        mx = fmaxf(mx, __shfl_xor(mx, 1));
        mx = fmaxf(mx, __shfl_xor(mx, 2));
        mx = fmaxf(mx, __shfl_xor(mx, 4));
        mx = fmaxf(mx, __shfl_xor(mx, 8));
        float mnew = fmaxf(mrow[r], mx);
        float alpha = exp2f(mrow[r] - mnew);
        mrow[r] = mnew;
        float p0 = exp2f(s0 - mnew), p1 = exp2f(s1 - mnew),
              p2 = exp2f(s2 - mnew), p3 = exp2f(s3 - mnew);
        lsum[r] = lsum[r] * alpha + ((p0 + p1) + (p2 + p3));
        #pragma unroll
        for (int nd = 0; nd < 8; ++nd) acc[nd][r] *= alpha;
        short* pr = &Ps[w][lg * 4 + r][0];
        pr[lr]      = f2bf(p0);
        pr[16 + lr] = f2bf(p1);
        pr[32 + lr] = f2bf(p2);
        pr[48 + lr] = f2bf(p3);
      }
      asm volatile("s_waitcnt lgkmcnt(0)" ::: "memory");
      __builtin_amdgcn_sched_barrier(0);

      short8 pf0 = *(const short8*)&Ps[w][lr][lg * 8];
      short8 pf1 = *(const short8*)&Ps[w][lr][32 + lg * 8];
      #pragma unroll
      for (int nd = 0; nd < 8; ++nd) {
        int rr = nd * 16 + lr;
        short8 vf0 = *(const short8*)&Vs[cur][(rr * 64 + lg * 8) ^ ((rr & 7) << 3)];
        short8 vf1 = *(const short8*)&Vs[cur][(rr * 64 + 32 + lg * 8) ^ ((rr & 7) << 3)];
        acc[nd] = MF(pf0, vf0, acc[nd]);
        acc[nd] = MF(pf1, vf1, acc[nd]);
      }
      __syncthreads();
      if (pre) {
        #pragma unroll
        for (int i = 0; i < 2; ++i) {
          int r = krr + 32 * i;
          *(uint4*)&Ks[cur ^ 1][(r * 128 + kcc) ^ ((r & 7) << 3)] = krg[i];
          int d = vdd + 64 * i;
          *(uint4*)&Vs[cur ^ 1][(d * 64 + vcc) ^ ((d & 7) << 3)] = vrg[i];
        }
      }
      __syncthreads();
      cur ^= 1;
    }

    float inv[4];
    #pragma unroll
    for (int r = 0; r < 4; ++r) {
      float ls = lsum[r];
      ls += __shfl_xor(ls, 1);
      ls += __shfl_xor(ls, 2);
      ls += __shfl_xor(ls, 4);
      ls += __shfl_xor(ls, 8);
      inv[r] = 1.0f / ls;
    }
    #pragma unroll
    for (int nd = 0; nd < 8; ++nd)
      #pragma unroll
      for (int r = 0; r < 4; ++r) {
        int row = qrow0 + lg * 4 + r;
        O[(size_t)(b * SEQ + row) * D_MODEL + h * DK + nd * 16 + lr] = f2bf(acc[nd][r] * inv[r]);
      }
  }
}

// ======== FALLBACK PATH (round-2 verified kernels) ========
template<int EPI>
__global__ __launch_bounds__(256) void gemm_bt(const short* __restrict__ A,
                                               const float* __restrict__ B,
                                               void* Cv,
                                               const float* resid,
                                               int M, int N, int K) {
  __shared__ __align__(16) short As[128][72];
  __shared__ __align__(16) short Bs[128][72];
  const int t = threadIdx.x;
  const int m0 = blockIdx.x * 128, n0 = blockIdx.y * 128;
  const int wave = t >> 6, lane = t & 63, lr = lane & 15, lg = lane >> 4;
  const int wr = (wave >> 1) * 64, wc = (wave & 1) * 64;

  f32x4 acc[4][4];
  const f32x4 z4 = {0.f, 0.f, 0.f, 0.f};
  #pragma unroll
  for (int m = 0; m < 4; ++m)
    #pragma unroll
    for (int n = 0; n < 4; ++n) acc[m][n] = z4;

  int ar[4], ac[4];
  #pragma unroll
  for (int i = 0; i < 4; ++i) { int u = t + 256*i; ar[i] = u >> 3; ac[i] = (u & 7) * 8; }

  for (int k0 = 0; k0 < K; k0 += 64) {
    #pragma unroll
    for (int i = 0; i < 4; ++i) {
      uint4 va = *(const uint4*)(A + (size_t)(m0 + ar[i]) * K + k0 + ac[i]);
      *(uint4*)&As[ar[i]][ac[i]] = va;
    }
    #pragma unroll
    for (int i = 0; i < 4; ++i) {
      const float4* bp = (const float4*)(B + (size_t)(n0 + ar[i]) * K + k0 + ac[i]);
      float4 b0 = bp[0], b1 = bp[1];
      short8 pb = { f2bf(b0.x), f2bf(b0.y), f2bf(b0.z), f2bf(b0.w),
                    f2bf(b1.x), f2bf(b1.y), f2bf(b1.z), f2bf(b1.w) };
      *(short8*)&Bs[ar[i]][ac[i]] = pb;
    }
    __syncthreads();
    #pragma unroll
    for (int kk = 0; kk < 64; kk += 32) {
      short8 af[4], bfr[4];
      #pragma unroll
      for (int m = 0; m < 4; ++m) af[m]  = *(const short8*)&As[wr + m*16 + lr][kk + lg*8];
      #pragma unroll
      for (int n = 0; n < 4; ++n) bfr[n] = *(const short8*)&Bs[wc + n*16 + lr][kk + lg*8];
      #pragma unroll
      for (int m = 0; m < 4; ++m)
        #pragma unroll
        for (int n = 0; n < 4; ++n)
          acc[m][n] = MF(af[m], bfr[n], acc[m][n]);
    }
    __syncthreads();
  }

  #pragma unroll
  for (int m = 0; m < 4; ++m)
    #pragma unroll
    for (int n = 0; n < 4; ++n)
      #pragma unroll
      for (int r = 0; r < 4; ++r) {
        int row = m0 + wr + m*16 + lg*4 + r;
        int col = n0 + wc + n*16 + lr;
        size_t idx = (size_t)row * N + col;
        float vv = acc[m][n][r];
        if (EPI == 0) {
          ((short*)Cv)[idx] = f2bf(vv);
        } else if (EPI == 1) {
          float gl = 0.5f * vv * (1.0f + erff(vv * 0.70710678118654752f));
          ((short*)Cv)[idx] = f2bf(gl);
        } else {
          ((float*)Cv)[idx] = vv + resid[idx];
        }
      }
}

__global__ __launch_bounds__(256) void attn_k(const short* __restrict__ Q,
                                              const short* __restrict__ K,
                                              const short* __restrict__ V,
                                              short* __restrict__ O) {
  const float scale = 0.08838834764831845f;
  const int qt = blockIdx.x;
  const int bh = blockIdx.y;
  const int b = bh >> 4, h = bh & 15;
  const size_t base = ((size_t)b * SEQ) * D_MODEL + (size_t)h * DK;
  const int t = threadIdx.x, wave = t >> 6, lane = t & 63, lr = lane & 15, lg = lane >> 4;

  __shared__ __align__(16) short Ks[32][136];
  __shared__ __align__(16) short Vt[128][40];
  __shared__ __align__(16) short Ps[4][32][40];

  const int qrow0 = qt * 128 + wave * 32;
  short8 qf[2][4];
  #pragma unroll
  for (int mq = 0; mq < 2; ++mq)
    #pragma unroll
    for (int ki = 0; ki < 4; ++ki)
      qf[mq][ki] = *(const short8*)(Q + base + (size_t)(qrow0 + mq*16 + lr) * D_MODEL + ki*32 + lg*8);

  f32x4 acc[2][8];
  const f32x4 z4 = {0.f, 0.f, 0.f, 0.f};
  #pragma unroll
  for (int mq = 0; mq < 2; ++mq)
    #pragma unroll
    for (int nd = 0; nd < 8; ++nd) acc[mq][nd] = z4;
  float mrow[2][4], lsum[2][4];
  #pragma unroll
  for (int mq = 0; mq < 2; ++mq)
    #pragma unroll
    for (int r = 0; r < 4; ++r) { mrow[mq][r] = -INFINITY; lsum[mq][r] = 0.f; }

  const int lastt = qt * 4 + 3;
  for (int tt = 0; tt <= lastt; ++tt) {
    #pragma unroll
    for (int i = 0; i < 2; ++i) {
      int u = t + 256*i; int r = u >> 4; int c = (u & 15) * 8;
      *(uint4*)&Ks[r][c] = *(const uint4*)(K + base + (size_t)(tt*32 + r) * D_MODEL + c);
      uint4 vv = *(const uint4*)(V + base + (size_t)(tt*32 + r) * D_MODEL + c);
      const short* sv = (const short*)&vv;
      #pragma unroll
      for (int j = 0; j < 8; ++j) Vt[c + j][r] = sv[j];
    }
    __syncthreads();
    if (tt <= qt * 4 + wave) {
      f32x4 sf[2][2] = {{z4, z4}, {z4, z4}};
      #pragma unroll
      for (int ki = 0; ki < 4; ++ki) {
        short8 kf0 = *(const short8*)&Ks[lr][ki*32 + lg*8];
        short8 kf1 = *(const short8*)&Ks[16 + lr][ki*32 + lg*8];
        sf[0][0] = MF(qf[0][ki], kf0, sf[0][0]);
        sf[0][1] = MF(qf[0][ki], kf1, sf[0][1]);
        sf[1][0] = MF(qf[1][ki], kf0, sf[1][0]);
        sf[1][1] = MF(qf[1][ki], kf1, sf[1][1]);
      }
      #pragma unroll
      for (int mq = 0; mq < 2; ++mq) {
        #pragma unroll
        for (int r = 0; r < 4; ++r) {
          int qg = qrow0 + mq*16 + lg*4 + r;
          float s0 = sf[mq][0][r] * scale;
          float s1 = sf[mq][1][r] * scale;
          if (tt*32 + lr > qg)       s0 = -INFINITY;
          if (tt*32 + 16 + lr > qg)  s1 = -INFINITY;
          float mx = fmaxf(s0, s1);
          mx = fmaxf(mx, __shfl_xor(mx, 1));
          mx = fmaxf(mx, __shfl_xor(mx, 2));
          mx = fmaxf(mx, __shfl_xor(mx, 4));
          mx = fmaxf(mx, __shfl_xor(mx, 8));
          float mnew = fmaxf(mrow[mq][r], mx);
          float alpha = __expf(mrow[mq][r] - mnew);
          mrow[mq][r] = mnew;
          float p0 = __expf(s0 - mnew);
          float p1 = __expf(s1 - mnew);
          float ps = p0 + p1;
          ps += __shfl_xor(ps, 1);
          ps += __shfl_xor(ps, 2);
          ps += __shfl_xor(ps, 4);
          ps += __shfl_xor(ps, 8);
          lsum[mq][r] = lsum[mq][r] * alpha + ps;
          #pragma unroll
          for (int nd = 0; nd < 8; ++nd) acc[mq][nd][r] *= alpha;
          Ps[wave][mq*16 + lg*4 + r][lr]      = f2bf(p0);
          Ps[wave][mq*16 + lg*4 + r][16 + lr] = f2bf(p1);
        }
      }
      asm volatile("s_waitcnt lgkmcnt(0)" ::: "memory");
      short8 pf0 = *(const short8*)&Ps[wave][lr][lg*8];
      short8 pf1 = *(const short8*)&Ps[wave][16 + lr][lg*8];
      #pragma unroll
      for (int nd = 0; nd < 8; ++nd) {
        short8 vf = *(const short8*)&Vt[nd*16 + lr][lg*8];
        acc[0][nd] = MF(pf0, vf, acc[0][nd]);
        acc[1][nd] = MF(pf1, vf, acc[1][nd]);
      }
    }
    __syncthreads();
  }

  #pragma unroll
  for (int mq = 0; mq < 2; ++mq)
    #pragma unroll
    for (int nd = 0; nd < 8; ++nd)
      #pragma unroll
      for (int r = 0; r < 4; ++r) {
        int row = qrow0 + mq*16 + lg*4 + r;
        O[base + (size_t)row * D_MODEL + nd*16 + lr] = f2bf(acc[mq][nd][r] / lsum[mq][r]);
      }
}

// ---------------- launch ----------------
extern "C" void kernel_launch(void* const* d_in, const int* in_sizes, int n_in,
                              void* d_out, int out_size, void* d_ws, size_t ws_size,
                              hipStream_t stream) {
  const float* x  = (const float*)d_in[0];
  const float* wq = (const float*)d_in[1];
  const float* wk = (const float*)d_in[2];
  const float* wv = (const float*)d_in[3];
  const float* wo = (const float*)d_in[4];
  const float* w1 = (const float*)d_in[5];
  const float* w2 = (const float*)d_in[6];
  const float* g1 = (const float*)d_in[7];
  const float* g2 = (const float*)d_in[8];
  float* out = (float*)d_out;
  char* ws = (char*)d_ws;

  const size_t NEED = (size_t)192 << 20;
  if (ws_size >= NEED) {
    // fast path layout (192 MiB):
    //   [0,24M) wqkv | [24,32M) wo | [32,64M) w1 | [64,96M) w2   (bf16 weights)
    //   [96,144M) qkv | [144,160M) vt | [160,176M) ab | [176,192M) xn
    //   FFN phase: hb = [96,160M); FFN2 split-K partials = [160,192M) (ab/xn dead)
    short* wqkv = (short*)(ws);
    short* wo_b = (short*)(ws + ((size_t)24 << 20));
    short* w1_b = (short*)(ws + ((size_t)32 << 20));
    short* w2_b = (short*)(ws + ((size_t)64 << 20));
    short* qkv  = (short*)(ws + ((size_t)96 << 20));
    short* vt   = (short*)(ws + ((size_t)144 << 20));
    short* ab   = (short*)(ws + ((size_t)160 << 20));
    short* xn   = (short*)(ws + ((size_t)176 << 20));
    short* hb   = (short*)(ws + ((size_t)96 << 20));
    float* pf   = (float*)(ws + ((size_t)160 << 20));   // 2x 32MB fp32 partials

    const int NW = D_MODEL * D_MODEL / 8;
    f2b_k<<<(NW + 255) / 256, 256, 0, stream>>>(wq, wqkv,                   NW);
    f2b_k<<<(NW + 255) / 256, 256, 0, stream>>>(wk, wqkv + (size_t)D_MODEL * D_MODEL,     NW);
    f2b_k<<<(NW + 255) / 256, 256, 0, stream>>>(wv, wqkv + (size_t)2 * D_MODEL * D_MODEL, NW);
    f2b_k<<<(NW + 255) / 256, 256, 0, stream>>>(wo, wo_b, NW);
    const int NF = DFF * D_MODEL / 8;
    f2b_k<<<(NF + 255) / 256, 256, 0, stream>>>(w1, w1_b, NF);
    f2b_k<<<(NF + 255) / 256, 256, 0, stream>>>(w2, w2_b, NF);

    rmsnorm_k<<<MROWS, 256, 0, stream>>>(x, g1, xn);
    // QKV: 16x24 = 384 blocks
    gemm256<0,0><<<dim3(16 * 24), 512, 0, stream>>>(xn, wqkv, qkv, nullptr,
                                                    MROWS, 6144, D_MODEL, D_MODEL, D_MODEL, 16);
    vtrans<<<dim3(SEQ/64, BATCH*NHEAD), 256, 0, stream>>>(qkv, vt);
    attn3<<<dim3(8, BATCH*NHEAD), 512, 0, stream>>>(qkv, vt, ab);
    // o-proj: 16x8 = 128 blocks, +resid
    gemm256<2,0><<<dim3(16 * 8), 512, 0, stream>>>(ab, wo_b, out, x,
                                                   MROWS, D_MODEL, D_MODEL, D_MODEL, D_MODEL, 16);
    rmsnorm_k<<<MROWS, 256, 0, stream>>>(out, g2, xn);
    // FFN1: 16x32 = 512 blocks, GELU
    gemm256<1,0><<<dim3(16 * 32), 512, 0, stream>>>(xn, w1_b, hb, nullptr,
                                                    MROWS, DFF, D_MODEL, D_MODEL, D_MODEL, 16);
    // FFN2: split-K x2 in one dispatch (16x8x2 = 256 blocks), then combine with resid
    gemm256<3,1><<<dim3(16 * 8 * 2), 512, 0, stream>>>(hb, w2_b, pf, nullptr,
                                                       MROWS, D_MODEL, DFF / 2, DFF, DFF, 16);
    const int N4 = MROWS * D_MODEL / 4;
    combine_k<<<(N4 + 255) / 256, 256, 0, stream>>>(pf, pf + (size_t)MROWS * D_MODEL, out, out, N4);
  } else {
    // fallback: round-2 verified path (80 MiB)
    short* qb = (short*)(ws + ((size_t)0  << 20));
    short* kb = (short*)(ws + ((size_t)16 << 20));
    short* vb = (short*)(ws + ((size_t)32 << 20));
    short* ab = (short*)(ws + ((size_t)48 << 20));
    short* xn = (short*)(ws + ((size_t)64 << 20));
    short* hb = (short*)(ws + ((size_t)0  << 20));

    dim3 gproj(MROWS / 128, D_MODEL / 128);
    rmsnorm_k<<<MROWS, 256, 0, stream>>>(x, g1, xn);
    gemm_bt<0><<<gproj, 256, 0, stream>>>(xn, wq, qb, nullptr, MROWS, D_MODEL, D_MODEL);
    gemm_bt<0><<<gproj, 256, 0, stream>>>(xn, wk, kb, nullptr, MROWS, D_MODEL, D_MODEL);
    gemm_bt<0><<<gproj, 256, 0, stream>>>(xn, wv, vb, nullptr, MROWS, D_MODEL, D_MODEL);
    attn_k<<<dim3(SEQ / 128, BATCH * NHEAD), 256, 0, stream>>>(qb, kb, vb, ab);
    gemm_bt<2><<<gproj, 256, 0, stream>>>(ab, wo, out, x, MROWS, D_MODEL, D_MODEL);
    rmsnorm_k<<<MROWS, 256, 0, stream>>>(out, g2, xn);
    for (int half = 0; half < 2; ++half) {
      const short* xh = xn  + (size_t)half * 2048 * D_MODEL;
      float*       oh = out + (size_t)half * 2048 * D_MODEL;
      gemm_bt<1><<<dim3(2048 / 128, DFF / 128), 256, 0, stream>>>(xh, w1, hb, nullptr, 2048, DFF, D_MODEL);
      gemm_bt<2><<<dim3(2048 / 128, D_MODEL / 128), 256, 0, stream>>>(hb, w2, oh, oh, 2048, D_MODEL, DFF);
    }
  }
}

// Round 9
// 771.093 us; speedup vs baseline: 1.0380x; 1.0380x over previous
//
#include <hip/hip_runtime.h>
#include <hip/hip_bf16.h>
#include <math.h>

// ---- problem constants ----
#define D_MODEL 2048
#define SEQ     2048
#define BATCH   2
#define NHEAD   16
#define DK      128
#define DFF     8192
#define MROWS   (BATCH*SEQ)   // 4096 rows

typedef short short8 __attribute__((ext_vector_type(8)));   // 8 bf16 in 4 VGPRs
typedef float f32x4  __attribute__((ext_vector_type(4)));

__device__ __forceinline__ short f2bf(float f) {
  union { __hip_bfloat16 b; short s; } u;
  u.b = __float2bfloat16(f);
  return u.s;
}

#define MF(a, b, c) __builtin_amdgcn_mfma_f32_16x16x32_bf16(a, b, c, 0, 0, 0)
// wave-uniform LDS base via m0, per-lane global addr, 16B/lane direct-to-LDS
#define STG(gptr, ldsbyte) { \
    unsigned _m0v = (unsigned)__builtin_amdgcn_readfirstlane((int)(ldsbyte)); \
    asm volatile("s_mov_b32 m0, %1\n\tglobal_load_lds_dwordx4 %0, off" \
                 :: "v"(gptr), "s"(_m0v) : "memory"); }

// ---------------- RMSNorm: fp32 in -> bf16 out ----------------
__global__ __launch_bounds__(256) void rmsnorm_k(const float* __restrict__ x,
                                                 const float* __restrict__ g,
                                                 short* __restrict__ o) {
  const int row = blockIdx.x;
  const int t = threadIdx.x;
  const float4* xr = (const float4*)(x + (size_t)row * D_MODEL);
  const float4* gr = (const float4*)g;
  float4 v0 = xr[2*t], v1 = xr[2*t+1];
  float s = v0.x*v0.x + v0.y*v0.y + v0.z*v0.z + v0.w*v0.w
          + v1.x*v1.x + v1.y*v1.y + v1.z*v1.z + v1.w*v1.w;
  #pragma unroll
  for (int off = 1; off < 64; off <<= 1) s += __shfl_xor(s, off);
  __shared__ float red[4];
  if ((t & 63) == 0) red[t >> 6] = s;
  __syncthreads();
  float tot = red[0] + red[1] + red[2] + red[3];
  float inv = rsqrtf(tot * (1.0f / D_MODEL) + 1e-5f);
  float4 g0 = gr[2*t], g1v = gr[2*t+1];
  short8 ov;
  ov[0] = f2bf(v0.x * inv * g0.x);
  ov[1] = f2bf(v0.y * inv * g0.y);
  ov[2] = f2bf(v0.z * inv * g0.z);
  ov[3] = f2bf(v0.w * inv * g0.w);
  ov[4] = f2bf(v1.x * inv * g1v.x);
  ov[5] = f2bf(v1.y * inv * g1v.y);
  ov[6] = f2bf(v1.z * inv * g1v.z);
  ov[7] = f2bf(v1.w * inv * g1v.w);
  *((short8*)(o + (size_t)row * D_MODEL) + t) = ov;
}

// ---------------- fp32 -> bf16 convert (weights, one-time) ----------------
__global__ __launch_bounds__(256) void f2b_k(const float* __restrict__ src,
                                             short* __restrict__ dst, int n8) {
  int i = blockIdx.x * 256 + threadIdx.x;
  if (i >= n8) return;
  const float4* s4 = (const float4*)src + 2 * (size_t)i;
  float4 a = s4[0], b = s4[1];
  short8 o = { f2bf(a.x), f2bf(a.y), f2bf(a.z), f2bf(a.w),
               f2bf(b.x), f2bf(b.y), f2bf(b.z), f2bf(b.w) };
  *((short8*)dst + i) = o;
}

// ======== 128x128 double-buffered GEMM, 2 blocks/CU for cross-block TLP ========
// C[M,N] = A[M,K](bf16) * B[N,K](bf16)^T. 256 thr = 4 waves (2M x 2N), wave 64x64.
// LDS: As/Bs [2 slots][128x64] = 64 KB -> 2 blocks/CU, independent barrier
// domains cover each other's vmcnt/barrier stalls (m97/m114 mechanism).
// XOR swizzle ((row&7)<<3 shorts), pre-swizzled global source + swizzled ds_read
// -> 0 bank conflicts (verified R7). Slot discipline: tile T reads slot T&1;
// tile T+1 staged into the other slot -> no intra-tile WAR; one vmcnt(0)+barrier
// per K-tile. EPI: 0 bf16; 1 GELU bf16; 2 +resid fp32.
template<int EPI>
__global__ __launch_bounds__(256, 2) void gemm128(const short* __restrict__ A,
                                                  const short* __restrict__ Bp,
                                                  void* Cv,
                                                  const float* __restrict__ resid,
                                                  int M, int N, int K, int nbx) {
  __shared__ __align__(16) short As[2][128 * 64];   // 32 KB
  __shared__ __align__(16) short Bs[2][128 * 64];   // 32 KB
  const int nk = K >> 6;
  const int cpx = gridDim.x >> 3;                   // grid % 8 == 0 (bijective XCD swizzle)
  const int lin = (blockIdx.x & 7) * cpx + (blockIdx.x >> 3);
  const int bx = lin % nbx, by = lin / nbx;         // bx fast: same-XCD blocks share B panel
  const int m0 = bx * 128, n0 = by * 128;
  const int t = threadIdx.x, w = t >> 6, lane = t & 63, lr = lane & 15, lg = lane >> 4;
  const int wm = w >> 1, wn = w & 1;
  const unsigned aByte = (unsigned)(size_t)(const __attribute__((address_space(3))) short*)&As[0][0];
  const unsigned bByte = (unsigned)(size_t)(const __attribute__((address_space(3))) short*)&Bs[0][0];

  // staging: thread t -> rows r+32i (i=0..3), 16B chunk c8; source col pre-swizzled
  const int r = t >> 3, c8 = t & 7;
  const int swc = (c8 ^ (r & 7)) << 3;              // (r+32i)&7 == r&7
  const short* pA = A  + (size_t)(m0 + r) * K + swc;
  const short* pB = Bp + (size_t)(n0 + r) * K + swc;
  const size_t l32 = (size_t)32 * K;
  // per-pass lds dest is linear: row*128B + c8*16B == w*1024 + i*4096 + lane*16
#define STAGE(tt, s) { \
    _Pragma("unroll") \
    for (int i_ = 0; i_ < 4; ++i_) \
      STG(pA + (size_t)(tt) * 64 + i_ * l32, \
          aByte + (unsigned)(s) * 16384u + (unsigned)(i_ * 4096 + w * 1024)); \
    _Pragma("unroll") \
    for (int i_ = 0; i_ < 4; ++i_) \
      STG(pB + (size_t)(tt) * 64 + i_ * l32, \
          bByte + (unsigned)(s) * 16384u + (unsigned)(i_ * 4096 + w * 1024)); }

  f32x4 acc[4][4];
  const f32x4 z4 = {0.f, 0.f, 0.f, 0.f};
  #pragma unroll
  for (int m = 0; m < 4; ++m)
    #pragma unroll
    for (int n = 0; n < 4; ++n) acc[m][n] = z4;

  const int rsw = (lr & 7) << 3;                    // lane-constant read swizzle (shorts)
#define COMPUTE(s) { \
    short8 af_[4][2], bf_[4][2]; \
    _Pragma("unroll") \
    for (int m = 0; m < 4; ++m) { \
      int ar_ = wm * 64 + m * 16 + lr; \
      af_[m][0] = *(const short8*)&As[s][ar_ * 64 + ((lg * 8) ^ rsw)]; \
      af_[m][1] = *(const short8*)&As[s][ar_ * 64 + ((32 + lg * 8) ^ rsw)]; \
    } \
    _Pragma("unroll") \
    for (int n = 0; n < 4; ++n) { \
      int br_ = wn * 64 + n * 16 + lr; \
      bf_[n][0] = *(const short8*)&Bs[s][br_ * 64 + ((lg * 8) ^ rsw)]; \
      bf_[n][1] = *(const short8*)&Bs[s][br_ * 64 + ((32 + lg * 8) ^ rsw)]; \
    } \
    _Pragma("unroll") \
    for (int m = 0; m < 4; ++m) \
      _Pragma("unroll") \
      for (int n = 0; n < 4; ++n) { \
        acc[m][n] = MF(af_[m][0], bf_[n][0], acc[m][n]); \
        acc[m][n] = MF(af_[m][1], bf_[n][1], acc[m][n]); \
      } }

  // prologue: stage tile 0 into slot 0
  STAGE(0, 0);
  asm volatile("s_waitcnt vmcnt(0)" ::: "memory");
  __builtin_amdgcn_s_barrier();

  for (int T = 0; T < nk; ++T) {
    const int p = T & 1;
    if (T + 1 < nk) STAGE(T + 1, p ^ 1);   // other slot: no WAR with tile-T readers
    COMPUTE(p);
    if (T + 1 < nk) {
      asm volatile("s_waitcnt vmcnt(0)" ::: "memory");  // covered by sibling block
      __builtin_amdgcn_s_barrier();
    }
  }
#undef STAGE
#undef COMPUTE

  // epilogue
  #pragma unroll
  for (int m = 0; m < 4; ++m)
    #pragma unroll
    for (int n = 0; n < 4; ++n)
      #pragma unroll
      for (int rr = 0; rr < 4; ++rr) {
        int row = m0 + wm * 64 + m * 16 + lg * 4 + rr;
        int col = n0 + wn * 64 + n * 16 + lr;
        size_t idx = (size_t)row * N + col;
        float vv = acc[m][n][rr];
        if (EPI == 0) {
          ((short*)Cv)[idx] = f2bf(vv);
        } else if (EPI == 1) {
          float gl = 0.5f * vv * (1.0f + erff(vv * 0.70710678118654752f));
          ((short*)Cv)[idx] = f2bf(gl);
        } else {
          ((float*)Cv)[idx] = vv + resid[idx];
        }
      }
}

// ---------------- V transpose: qkv[.., v cols] -> vt[b][h][d][s] ----------------
__global__ __launch_bounds__(256) void vtrans(const short* __restrict__ QKV,
                                              short* __restrict__ VT) {
  const int st = blockIdx.x;   // s tile of 64
  const int bh = blockIdx.y;
  const int b = bh >> 4, h = bh & 15;
  const int t = threadIdx.x;
  __shared__ __align__(16) short T[64 * 128];
  const short* Vsrc = QKV + ((size_t)b * SEQ) * 6144 + 2 * D_MODEL + h * DK;
  {
    int r = t >> 4, c = (t & 15) * 8;
    #pragma unroll
    for (int i = 0; i < 4; ++i) {
      int rr = r + 16 * i;
      uint4 vv = *(const uint4*)(Vsrc + (size_t)(st * 64 + rr) * 6144 + c);
      *(uint4*)&T[rr * 128 + (c ^ (((rr >> 3) & 7) << 3))] = vv;
    }
  }
  __syncthreads();
  short* dst = VT + ((size_t)bh * DK) * SEQ + st * 64;
  {
    int c2 = (t & 7) * 8;
    #pragma unroll
    for (int i = 0; i < 4; ++i) {
      int d = (t >> 3) + 32 * i;
      short8 ov;
      #pragma unroll
      for (int j = 0; j < 8; ++j)
        ov[j] = T[(c2 + j) * 128 + (d ^ ((((c2 + j) >> 3) & 7) << 3))];
      *(short8*)(dst + (size_t)d * SEQ + c2) = ov;
    }
  }
}

// ---------------- Flash attention v3 (round-4 verified) ----------------
__global__ __launch_bounds__(512, 2) void attn3(const short* __restrict__ QKV,
                                                const short* __restrict__ VT,
                                                short* __restrict__ O) {
  const float SC = 0.12751743f;   // (1/sqrt(128)) * log2(e)
  const int a = blockIdx.x, bh = blockIdx.y;
  const int b = bh >> 4, h = bh & 15;
  const int t = threadIdx.x, w = t >> 6, lane = t & 63, lr = lane & 15, lg = lane >> 4;
  const short* Qp = QKV + ((size_t)b * SEQ) * 6144 + h * DK;
  const short* Kp = Qp + D_MODEL;
  const short* Vp = VT + ((size_t)bh * DK) * SEQ;   // [d][s]
  __shared__ __align__(16) short Ks[2][64 * 128];
  __shared__ __align__(16) short Vs[2][128 * 64];
  __shared__ __align__(16) short Ps[8][16][72];

  const int krr = t >> 4, kcc = (t & 15) * 8;
  const int vdd = t >> 3, vcc = (t & 7) * 8;
  const f32x4 z4 = {0.f, 0.f, 0.f, 0.f};

  for (int sub = 0; sub < 2; ++sub) {
    const int ts = sub ? (15 - a) : a;
    const int nt = 2 * ts + 2;
    const int qrow0 = ts * 128 + w * 16;

    short8 qf[4];
    #pragma unroll
    for (int ki = 0; ki < 4; ++ki)
      qf[ki] = *(const short8*)(Qp + (size_t)(qrow0 + lr) * 6144 + ki * 32 + lg * 8);

    f32x4 acc[8];
    #pragma unroll
    for (int nd = 0; nd < 8; ++nd) acc[nd] = z4;
    float mrow[4], lsum[4];
    #pragma unroll
    for (int r = 0; r < 4; ++r) { mrow[r] = -INFINITY; lsum[r] = 0.f; }

    uint4 krg[2], vrg[2];
    #pragma unroll
    for (int i = 0; i < 2; ++i) {
      krg[i] = *(const uint4*)(Kp + (size_t)(krr + 32 * i) * 6144 + kcc);
      vrg[i] = *(const uint4*)(Vp + (size_t)(vdd + 64 * i) * SEQ + vcc);
    }
    __syncthreads();
    #pragma unroll
    for (int i = 0; i < 2; ++i) {
      int r = krr + 32 * i;
      *(uint4*)&Ks[0][(r * 128 + kcc) ^ ((r & 7) << 3)] = krg[i];
      int d = vdd + 64 * i;
      *(uint4*)&Vs[0][(d * 64 + vcc) ^ ((d & 7) << 3)] = vrg[i];
    }
    __syncthreads();

    int cur = 0;
    for (int tt = 0; tt < nt; ++tt) {
      const bool pre = (tt + 1 < nt);
      if (pre) {
        #pragma unroll
        for (int i = 0; i < 2; ++i) {
          krg[i] = *(const uint4*)(Kp + (size_t)((tt + 1) * 64 + krr + 32 * i) * 6144 + kcc);
          vrg[i] = *(const uint4*)(Vp + (size_t)(vdd + 64 * i) * SEQ + (tt + 1) * 64 + vcc);
        }
      }

      f32x4 sf[4] = {z4, z4, z4, z4};
      #pragma unroll
      for (int ki = 0; ki < 4; ++ki) {
        #pragma unroll
        for (int nk = 0; nk < 4; ++nk) {
          int rr = nk * 16 + lr;
          short8 kf = *(const short8*)&Ks[cur][(rr * 128 + ki * 32 + lg * 8) ^ ((rr & 7) << 3)];
          sf[nk] = MF(qf[ki], kf, sf[nk]);
        }
      }

      const bool diag = (tt * 64 + 63 > qrow0);
      #pragma unroll
      for (int r = 0; r < 4; ++r) {
        int qg = qrow0 + lg * 4 + r;
        float s0 = sf[0][r] * SC, s1 = sf[1][r] * SC, s2 = sf[2][r] * SC, s3 = sf[3][r] * SC;
        if (diag) {
          int c0 = tt * 64 + lr;
          s0 = (c0      <= qg) ? s0 : -3.0e38f;
          s1 = (c0 + 16 <= qg) ? s1 : -3.0e38f;
          s2 = (c0 + 32 <= qg) ? s2 : -3.0e38f;
          s3 = (c0 + 48 <= qg) ? s3 : -3.0e38f;
        }
        float mx = fmaxf(fmaxf(s0, s1), fmaxf(s2, s3));
        mx = fmaxf(mx, __shfl_xor(mx, 1));
        mx = fmaxf(mx, __shfl_xor(mx, 2));
        mx = fmaxf(mx, __shfl_xor(mx, 4));
        mx = fmaxf(mx, __shfl_xor(mx, 8));
        float mnew = fmaxf(mrow[r], mx);
        float alpha = exp2f(mrow[r] - mnew);
        mrow[r] = mnew;
        float p0 = exp2f(s0 - mnew), p1 = exp2f(s1 - mnew),
              p2 = exp2f(s2 - mnew), p3 = exp2f(s3 - mnew);
        lsum[r] = lsum[r] * alpha + ((p0 + p1) + (p2 + p3));
        #pragma unroll
        for (int nd = 0; nd < 8; ++nd) acc[nd][r] *= alpha;
        short* pr = &Ps[w][lg * 4 + r][0];
        pr[lr]      = f2bf(p0);
        pr[16 + lr] = f2bf(p1);
        pr[32 + lr] = f2bf(p2);
        pr[48 + lr] = f2bf(p3);
      }
      asm volatile("s_waitcnt lgkmcnt(0)" ::: "memory");
      __builtin_amdgcn_sched_barrier(0);

      short8 pf0 = *(const short8*)&Ps[w][lr][lg * 8];
      short8 pf1 = *(const short8*)&Ps[w][lr][32 + lg * 8];
      #pragma unroll
      for (int nd = 0; nd < 8; ++nd) {
        int rr = nd * 16 + lr;
        short8 vf0 = *(const short8*)&Vs[cur][(rr * 64 + lg * 8) ^ ((rr & 7) << 3)];
        short8 vf1 = *(const short8*)&Vs[cur][(rr * 64 + 32 + lg * 8) ^ ((rr & 7) << 3)];
        acc[nd] = MF(pf0, vf0, acc[nd]);
        acc[nd] = MF(pf1, vf1, acc[nd]);
      }
      __syncthreads();
      if (pre) {
        #pragma unroll
        for (int i = 0; i < 2; ++i) {
          int r = krr + 32 * i;
          *(uint4*)&Ks[cur ^ 1][(r * 128 + kcc) ^ ((r & 7) << 3)] = krg[i];
          int d = vdd + 64 * i;
          *(uint4*)&Vs[cur ^ 1][(d * 64 + vcc) ^ ((d & 7) << 3)] = vrg[i];
        }
      }
      __syncthreads();
      cur ^= 1;
    }

    float inv[4];
    #pragma unroll
    for (int r = 0; r < 4; ++r) {
      float ls = lsum[r];
      ls += __shfl_xor(ls, 1);
      ls += __shfl_xor(ls, 2);
      ls += __shfl_xor(ls, 4);
      ls += __shfl_xor(ls, 8);
      inv[r] = 1.0f / ls;
    }
    #pragma unroll
    for (int nd = 0; nd < 8; ++nd)
      #pragma unroll
      for (int r = 0; r < 4; ++r) {
        int row = qrow0 + lg * 4 + r;
        O[(size_t)(b * SEQ + row) * D_MODEL + h * DK + nd * 16 + lr] = f2bf(acc[nd][r] * inv[r]);
      }
  }
}

// ======== FALLBACK PATH (round-2 verified kernels) ========
template<int EPI>
__global__ __launch_bounds__(256) void gemm_bt(const short* __restrict__ A,
                                               const float* __restrict__ B,
                                               void* Cv,
                                               const float* resid,
                                               int M, int N, int K) {
  __shared__ __align__(16) short As[128][72];
  __shared__ __align__(16) short Bs[128][72];
  const int t = threadIdx.x;
  const int m0 = blockIdx.x * 128, n0 = blockIdx.y * 128;
  const int wave = t >> 6, lane = t & 63, lr = lane & 15, lg = lane >> 4;
  const int wr = (wave >> 1) * 64, wc = (wave & 1) * 64;

  f32x4 acc[4][4];
  const f32x4 z4 = {0.f, 0.f, 0.f, 0.f};
  #pragma unroll
  for (int m = 0; m < 4; ++m)
    #pragma unroll
    for (int n = 0; n < 4; ++n) acc[m][n] = z4;

  int ar[4], ac[4];
  #pragma unroll
  for (int i = 0; i < 4; ++i) { int u = t + 256*i; ar[i] = u >> 3; ac[i] = (u & 7) * 8; }

  for (int k0 = 0; k0 < K; k0 += 64) {
    #pragma unroll
    for (int i = 0; i < 4; ++i) {
      uint4 va = *(const uint4*)(A + (size_t)(m0 + ar[i]) * K + k0 + ac[i]);
      *(uint4*)&As[ar[i]][ac[i]] = va;
    }
    #pragma unroll
    for (int i = 0; i < 4; ++i) {
      const float4* bp = (const float4*)(B + (size_t)(n0 + ar[i]) * K + k0 + ac[i]);
      float4 b0 = bp[0], b1 = bp[1];
      short8 pb = { f2bf(b0.x), f2bf(b0.y), f2bf(b0.z), f2bf(b0.w),
                    f2bf(b1.x), f2bf(b1.y), f2bf(b1.z), f2bf(b1.w) };
      *(short8*)&Bs[ar[i]][ac[i]] = pb;
    }
    __syncthreads();
    #pragma unroll
    for (int kk = 0; kk < 64; kk += 32) {
      short8 af[4], bfr[4];
      #pragma unroll
      for (int m = 0; m < 4; ++m) af[m]  = *(const short8*)&As[wr + m*16 + lr][kk + lg*8];
      #pragma unroll
      for (int n = 0; n < 4; ++n) bfr[n] = *(const short8*)&Bs[wc + n*16 + lr][kk + lg*8];
      #pragma unroll
      for (int m = 0; m < 4; ++m)
        #pragma unroll
        for (int n = 0; n < 4; ++n)
          acc[m][n] = MF(af[m], bfr[n], acc[m][n]);
    }
    __syncthreads();
  }

  #pragma unroll
  for (int m = 0; m < 4; ++m)
    #pragma unroll
    for (int n = 0; n < 4; ++n)
      #pragma unroll
      for (int r = 0; r < 4; ++r) {
        int row = m0 + wr + m*16 + lg*4 + r;
        int col = n0 + wc + n*16 + lr;
        size_t idx = (size_t)row * N + col;
        float vv = acc[m][n][r];
        if (EPI == 0) {
          ((short*)Cv)[idx] = f2bf(vv);
        } else if (EPI == 1) {
          float gl = 0.5f * vv * (1.0f + erff(vv * 0.70710678118654752f));
          ((short*)Cv)[idx] = f2bf(gl);
        } else {
          ((float*)Cv)[idx] = vv + resid[idx];
        }
      }
}

__global__ __launch_bounds__(256) void attn_k(const short* __restrict__ Q,
                                              const short* __restrict__ K,
                                              const short* __restrict__ V,
                                              short* __restrict__ O) {
  const float scale = 0.08838834764831845f;
  const int qt = blockIdx.x;
  const int bh = blockIdx.y;
  const int b = bh >> 4, h = bh & 15;
  const size_t base = ((size_t)b * SEQ) * D_MODEL + (size_t)h * DK;
  const int t = threadIdx.x, wave = t >> 6, lane = t & 63, lr = lane & 15, lg = lane >> 4;

  __shared__ __align__(16) short Ks[32][136];
  __shared__ __align__(16) short Vt[128][40];
  __shared__ __align__(16) short Ps[4][32][40];

  const int qrow0 = qt * 128 + wave * 32;
  short8 qf[2][4];
  #pragma unroll
  for (int mq = 0; mq < 2; ++mq)
    #pragma unroll
    for (int ki = 0; ki < 4; ++ki)
      qf[mq][ki] = *(const short8*)(Q + base + (size_t)(qrow0 + mq*16 + lr) * D_MODEL + ki*32 + lg*8);

  f32x4 acc[2][8];
  const f32x4 z4 = {0.f, 0.f, 0.f, 0.f};
  #pragma unroll
  for (int mq = 0; mq < 2; ++mq)
    #pragma unroll
    for (int nd = 0; nd < 8; ++nd) acc[mq][nd] = z4;
  float mrow[2][4], lsum[2][4];
  #pragma unroll
  for (int mq = 0; mq < 2; ++mq)
    #pragma unroll
    for (int r = 0; r < 4; ++r) { mrow[mq][r] = -INFINITY; lsum[mq][r] = 0.f; }

  const int lastt = qt * 4 + 3;
  for (int tt = 0; tt <= lastt; ++tt) {
    #pragma unroll
    for (int i = 0; i < 2; ++i) {
      int u = t + 256*i; int r = u >> 4; int c = (u & 15) * 8;
      *(uint4*)&Ks[r][c] = *(const uint4*)(K + base + (size_t)(tt*32 + r) * D_MODEL + c);
      uint4 vv = *(const uint4*)(V + base + (size_t)(tt*32 + r) * D_MODEL + c);
      const short* sv = (const short*)&vv;
      #pragma unroll
      for (int j = 0; j < 8; ++j) Vt[c + j][r] = sv[j];
    }
    __syncthreads();
    if (tt <= qt * 4 + wave) {
      f32x4 sf[2][2] = {{z4, z4}, {z4, z4}};
      #pragma unroll
      for (int ki = 0; ki < 4; ++ki) {
        short8 kf0 = *(const short8*)&Ks[lr][ki*32 + lg*8];
        short8 kf1 = *(const short8*)&Ks[16 + lr][ki*32 + lg*8];
        sf[0][0] = MF(qf[0][ki], kf0, sf[0][0]);
        sf[0][1] = MF(qf[0][ki], kf1, sf[0][1]);
        sf[1][0] = MF(qf[1][ki], kf0, sf[1][0]);
        sf[1][1] = MF(qf[1][ki], kf1, sf[1][1]);
      }
      #pragma unroll
      for (int mq = 0; mq < 2; ++mq) {
        #pragma unroll
        for (int r = 0; r < 4; ++r) {
          int qg = qrow0 + mq*16 + lg*4 + r;
          float s0 = sf[mq][0][r] * scale;
          float s1 = sf[mq][1][r] * scale;
          if (tt*32 + lr > qg)       s0 = -INFINITY;
          if (tt*32 + 16 + lr > qg)  s1 = -INFINITY;
          float mx = fmaxf(s0, s1);
          mx = fmaxf(mx, __shfl_xor(mx, 1));
          mx = fmaxf(mx, __shfl_xor(mx, 2));
          mx = fmaxf(mx, __shfl_xor(mx, 4));
          mx = fmaxf(mx, __shfl_xor(mx, 8));
          float mnew = fmaxf(mrow[mq][r], mx);
          float alpha = __expf(mrow[mq][r] - mnew);
          mrow[mq][r] = mnew;
          float p0 = __expf(s0 - mnew);
          float p1 = __expf(s1 - mnew);
          float ps = p0 + p1;
          ps += __shfl_xor(ps, 1);
          ps += __shfl_xor(ps, 2);
          ps += __shfl_xor(ps, 4);
          ps += __shfl_xor(ps, 8);
          lsum[mq][r] = lsum[mq][r] * alpha + ps;
          #pragma unroll
          for (int nd = 0; nd < 8; ++nd) acc[mq][nd][r] *= alpha;
          Ps[wave][mq*16 + lg*4 + r][lr]      = f2bf(p0);
          Ps[wave][mq*16 + lg*4 + r][16 + lr] = f2bf(p1);
        }
      }
      asm volatile("s_waitcnt lgkmcnt(0)" ::: "memory");
      short8 pf0 = *(const short8*)&Ps[wave][lr][lg*8];
      short8 pf1 = *(const short8*)&Ps[wave][16 + lr][lg*8];
      #pragma unroll
      for (int nd = 0; nd < 8; ++nd) {
        short8 vf = *(const short8*)&Vt[nd*16 + lr][lg*8];
        acc[0][nd] = MF(pf0, vf, acc[0][nd]);
        acc[1][nd] = MF(pf1, vf, acc[1][nd]);
      }
    }
    __syncthreads();
  }

  #pragma unroll
  for (int mq = 0; mq < 2; ++mq)
    #pragma unroll
    for (int nd = 0; nd < 8; ++nd)
      #pragma unroll
      for (int r = 0; r < 4; ++r) {
        int row = qrow0 + mq*16 + lg*4 + r;
        O[base + (size_t)row * D_MODEL + nd*16 + lr] = f2bf(acc[mq][nd][r] / lsum[mq][r]);
      }
}

// ---------------- launch ----------------
extern "C" void kernel_launch(void* const* d_in, const int* in_sizes, int n_in,
                              void* d_out, int out_size, void* d_ws, size_t ws_size,
                              hipStream_t stream) {
  const float* x  = (const float*)d_in[0];
  const float* wq = (const float*)d_in[1];
  const float* wk = (const float*)d_in[2];
  const float* wv = (const float*)d_in[3];
  const float* wo = (const float*)d_in[4];
  const float* w1 = (const float*)d_in[5];
  const float* w2 = (const float*)d_in[6];
  const float* g1 = (const float*)d_in[7];
  const float* g2 = (const float*)d_in[8];
  float* out = (float*)d_out;
  char* ws = (char*)d_ws;

  const size_t NEED = (size_t)192 << 20;
  if (ws_size >= NEED) {
    // fast path layout (192 MiB):
    //   [0,24M) wqkv | [24,32M) wo | [32,64M) w1 | [64,96M) w2   (bf16 weights)
    //   [96,144M) qkv | [144,160M) vt | [160,176M) ab | [176,192M) xn
    //   FFN phase: hb = [96,160M)
    short* wqkv = (short*)(ws);
    short* wo_b = (short*)(ws + ((size_t)24 << 20));
    short* w1_b = (short*)(ws + ((size_t)32 << 20));
    short* w2_b = (short*)(ws + ((size_t)64 << 20));
    short* qkv  = (short*)(ws + ((size_t)96 << 20));
    short* vt   = (short*)(ws + ((size_t)144 << 20));
    short* ab   = (short*)(ws + ((size_t)160 << 20));
    short* xn   = (short*)(ws + ((size_t)176 << 20));
    short* hb   = (short*)(ws + ((size_t)96 << 20));

    const int NW = D_MODEL * D_MODEL / 8;
    f2b_k<<<(NW + 255) / 256, 256, 0, stream>>>(wq, wqkv,                   NW);
    f2b_k<<<(NW + 255) / 256, 256, 0, stream>>>(wk, wqkv + (size_t)D_MODEL * D_MODEL,     NW);
    f2b_k<<<(NW + 255) / 256, 256, 0, stream>>>(wv, wqkv + (size_t)2 * D_MODEL * D_MODEL, NW);
    f2b_k<<<(NW + 255) / 256, 256, 0, stream>>>(wo, wo_b, NW);
    const int NF = DFF * D_MODEL / 8;
    f2b_k<<<(NF + 255) / 256, 256, 0, stream>>>(w1, w1_b, NF);
    f2b_k<<<(NF + 255) / 256, 256, 0, stream>>>(w2, w2_b, NF);

    rmsnorm_k<<<MROWS, 256, 0, stream>>>(x, g1, xn);
    // QKV: 32x48 = 1536 blocks
    gemm128<0><<<dim3(32 * 48), 256, 0, stream>>>(xn, wqkv, qkv, nullptr,
                                                  MROWS, 6144, D_MODEL, 32);
    vtrans<<<dim3(SEQ/64, BATCH*NHEAD), 256, 0, stream>>>(qkv, vt);
    attn3<<<dim3(8, BATCH*NHEAD), 512, 0, stream>>>(qkv, vt, ab);
    // o-proj: 32x16 = 512 blocks, +resid
    gemm128<2><<<dim3(32 * 16), 256, 0, stream>>>(ab, wo_b, out, x,
                                                  MROWS, D_MODEL, D_MODEL, 32);
    rmsnorm_k<<<MROWS, 256, 0, stream>>>(out, g2, xn);
    // FFN1: 32x64 = 2048 blocks, GELU
    gemm128<1><<<dim3(32 * 64), 256, 0, stream>>>(xn, w1_b, hb, nullptr,
                                                  MROWS, DFF, D_MODEL, 32);
    // FFN2: 32x16 = 512 blocks, in-place residual on d_out
    gemm128<2><<<dim3(32 * 16), 256, 0, stream>>>(hb, w2_b, out, out,
                                                  MROWS, D_MODEL, DFF, 32);
  } else {
    // fallback: round-2 verified path (80 MiB)
    short* qb = (short*)(ws + ((size_t)0  << 20));
    short* kb = (short*)(ws + ((size_t)16 << 20));
    short* vb = (short*)(ws + ((size_t)32 << 20));
    short* ab = (short*)(ws + ((size_t)48 << 20));
    short* xn = (short*)(ws + ((size_t)64 << 20));
    short* hb = (short*)(ws + ((size_t)0  << 20));

    dim3 gproj(MROWS / 128, D_MODEL / 128);
    rmsnorm_k<<<MROWS, 256, 0, stream>>>(x, g1, xn);
    gemm_bt<0><<<gproj, 256, 0, stream>>>(xn, wq, qb, nullptr, MROWS, D_MODEL, D_MODEL);
    gemm_bt<0><<<gproj, 256, 0, stream>>>(xn, wk, kb, nullptr, MROWS, D_MODEL, D_MODEL);
    gemm_bt<0><<<gproj, 256, 0, stream>>>(xn, wv, vb, nullptr, MROWS, D_MODEL, D_MODEL);
    attn_k<<<dim3(SEQ / 128, BATCH * NHEAD), 256, 0, stream>>>(qb, kb, vb, ab);
    gemm_bt<2><<<gproj, 256, 0, stream>>>(ab, wo, out, x, MROWS, D_MODEL, D_MODEL);
    rmsnorm_k<<<MROWS, 256, 0, stream>>>(out, g2, xn);
    for (int half = 0; half < 2; ++half) {
      const short* xh = xn  + (size_t)half * 2048 * D_MODEL;
      float*       oh = out + (size_t)half * 2048 * D_MODEL;
      gemm_bt<1><<<dim3(2048 / 128, DFF / 128), 256, 0, stream>>>(xh, w1, hb, nullptr, 2048, DFF, D_MODEL);
      gemm_bt<2><<<dim3(2048 / 128, D_MODEL / 128), 256, 0, stream>>>(hb, w2, oh, oh, 2048, D_MODEL, DFF);
    }
  }
}

// Round 10
// 757.055 us; speedup vs baseline: 1.0572x; 1.0185x over previous
//
#include <hip/hip_runtime.h>
#include <hip/hip_bf16.h>
#include <math.h>

// ---- problem constants ----
#define D_MODEL 2048
#define SEQ     2048
#define BATCH   2
#define NHEAD   16
#define DK      128
#define DFF     8192
#define MROWS   (BATCH*SEQ)   // 4096 rows

typedef short short8 __attribute__((ext_vector_type(8)));   // 8 bf16 in 4 VGPRs
typedef float f32x4  __attribute__((ext_vector_type(4)));

__device__ __forceinline__ short f2bf(float f) {
  union { __hip_bfloat16 b; short s; } u;
  u.b = __float2bfloat16(f);
  return u.s;
}
__device__ __forceinline__ float bf2f(short s) {
  union { unsigned u; float f; } u;
  u.u = ((unsigned)(unsigned short)s) << 16;
  return u.f;
}

#define MF(a, b, c) __builtin_amdgcn_mfma_f32_16x16x32_bf16(a, b, c, 0, 0, 0)

__device__ __forceinline__ void gload_lds16(const void* g, void* l) {
  __builtin_amdgcn_global_load_lds(
      (const __attribute__((address_space(1))) unsigned int*)g,
      (__attribute__((address_space(3))) unsigned int*)l, 16, 0, 0);
}

// ---------------- RMSNorm: fp32 in -> bf16 out ----------------
__global__ __launch_bounds__(256) void rmsnorm_k(const float* __restrict__ x,
                                                 const float* __restrict__ g,
                                                 short* __restrict__ o) {
  const int row = blockIdx.x;
  const int t = threadIdx.x;
  const float4* xr = (const float4*)(x + (size_t)row * D_MODEL);
  const float4* gr = (const float4*)g;
  float4 v0 = xr[2*t], v1 = xr[2*t+1];
  float s = v0.x*v0.x + v0.y*v0.y + v0.z*v0.z + v0.w*v0.w
          + v1.x*v1.x + v1.y*v1.y + v1.z*v1.z + v1.w*v1.w;
  #pragma unroll
  for (int off = 1; off < 64; off <<= 1) s += __shfl_xor(s, off);
  __shared__ float red[4];
  if ((t & 63) == 0) red[t >> 6] = s;
  __syncthreads();
  float tot = red[0] + red[1] + red[2] + red[3];
  float inv = rsqrtf(tot * (1.0f / D_MODEL) + 1e-5f);
  float4 g0 = gr[2*t], g1v = gr[2*t+1];
  short8 ov;
  ov[0] = f2bf(v0.x * inv * g0.x);
  ov[1] = f2bf(v0.y * inv * g0.y);
  ov[2] = f2bf(v0.z * inv * g0.z);
  ov[3] = f2bf(v0.w * inv * g0.w);
  ov[4] = f2bf(v1.x * inv * g1v.x);
  ov[5] = f2bf(v1.y * inv * g1v.y);
  ov[6] = f2bf(v1.z * inv * g1v.z);
  ov[7] = f2bf(v1.w * inv * g1v.w);
  *((short8*)(o + (size_t)row * D_MODEL) + t) = ov;
}

// ---------------- fp32 -> bf16 convert (weights, one-time) ----------------
__global__ __launch_bounds__(256) void f2b_k(const float* __restrict__ src,
                                             short* __restrict__ dst, int n8) {
  int i = blockIdx.x * 256 + threadIdx.x;
  if (i >= n8) return;
  const float4* s4 = (const float4*)src + 2 * (size_t)i;
  float4 a = s4[0], b = s4[1];
  short8 o = { f2bf(a.x), f2bf(a.y), f2bf(a.z), f2bf(a.w),
               f2bf(b.x), f2bf(b.y), f2bf(b.z), f2bf(b.w) };
  *((short8*)dst + i) = o;
}

// ---------------- split-K combine: o = bf16(p0) + bf16(p1) + fp32(r) ----------------
__global__ __launch_bounds__(256) void combine_bb(const short* __restrict__ p0,
                                                  const short* __restrict__ p1,
                                                  const float* __restrict__ r,
                                                  float* __restrict__ o, int n8) {
  int i = blockIdx.x * 256 + threadIdx.x;
  if (i >= n8) return;
  short8 a = ((const short8*)p0)[i];
  short8 b = ((const short8*)p1)[i];
  float4 r0 = ((const float4*)r)[2 * (size_t)i];
  float4 r1 = ((const float4*)r)[2 * (size_t)i + 1];
  float4 o0, o1;
  o0.x = bf2f(a[0]) + bf2f(b[0]) + r0.x;
  o0.y = bf2f(a[1]) + bf2f(b[1]) + r0.y;
  o0.z = bf2f(a[2]) + bf2f(b[2]) + r0.z;
  o0.w = bf2f(a[3]) + bf2f(b[3]) + r0.w;
  o1.x = bf2f(a[4]) + bf2f(b[4]) + r1.x;
  o1.y = bf2f(a[5]) + bf2f(b[5]) + r1.y;
  o1.z = bf2f(a[6]) + bf2f(b[6]) + r1.z;
  o1.w = bf2f(a[7]) + bf2f(b[7]) + r1.w;
  ((float4*)o)[2 * (size_t)i]     = o0;
  ((float4*)o)[2 * (size_t)i + 1] = o1;
}

// ======== 128x128 single-buffer GEMM, 4 blocks/CU (m97 mechanism + 0-conflict swizzle) ========
// C[M,N] = A[M,K](bf16) * B[N,K](bf16)^T. 256 thr = 4 waves (2M x 2N), wave 64x64.
// LDS: As/Bs [128x64] = 32 KB total -> 4 blocks/CU (launch_bounds(256,4)); four
// independent barrier domains de-correlate the per-tile load-latency drains
// (m97/m114 mechanism). Control flow is m97-exact: stage -> __syncthreads ->
// compute -> __syncthreads, with the BUILTIN global_load_lds so the compiler
// inserts the correct vmcnt/lgkm waits at each barrier. XOR swizzle
// ((row&7)<<3 shorts) via pre-swizzled global source + swizzled ds_read
// -> 0 bank conflicts (verified R7/R9). EPI: 0 bf16; 1 GELU bf16; 2 +resid fp32.
// SPLIT: split-K x2, bf16 partials at Cv + ks*M*N.
template<int EPI, int SPLIT>
__global__ __launch_bounds__(256, 4) void gemm128s(const short* __restrict__ A,
                                                   const short* __restrict__ Bp,
                                                   void* Cv,
                                                   const float* __restrict__ resid,
                                                   int M, int N, int Kloop,
                                                   int lda, int nbx) {
  __shared__ __align__(16) short As[128 * 64];   // 16 KB
  __shared__ __align__(16) short Bs[128 * 64];   // 16 KB
  const int nk = Kloop >> 6;
  const int cpx = gridDim.x >> 3;                // grid % 8 == 0 (bijective XCD swizzle)
  const int lin = (blockIdx.x & 7) * cpx + (blockIdx.x >> 3);
  const int bx = lin % nbx;
  int row2 = lin / nbx, by, ks = 0;
  if (SPLIT) { ks = row2 & 1; by = row2 >> 1; } else { by = row2; }
  const int m0 = bx * 128, n0 = by * 128;
  if (SPLIT) { A += (size_t)ks * Kloop; Bp += (size_t)ks * Kloop; }

  const int t = threadIdx.x, w = t >> 6, lane = t & 63, lr = lane & 15, lg = lane >> 4;
  const int wm = w >> 1, wn = w & 1;

  // staging: thread t -> rows r+32i (i=0..3), 16B chunk c8; source col pre-swizzled
  const int r = t >> 3, c8 = t & 7;
  const int swc = (c8 ^ (r & 7)) << 3;           // (r+32i)&7 == r&7
  const short* pA = A  + (size_t)(m0 + r) * lda + swc;
  const short* pB = Bp + (size_t)(n0 + r) * lda + swc;
  const size_t l32 = (size_t)32 * lda;
  // LDS dest is linear: per-wave uniform base &As[i*2048 + w*512] (+ lane*16B by HW)

  f32x4 acc[4][4];
  const f32x4 z4 = {0.f, 0.f, 0.f, 0.f};
  #pragma unroll
  for (int m = 0; m < 4; ++m)
    #pragma unroll
    for (int n = 0; n < 4; ++n) acc[m][n] = z4;

  const int rsw = (lr & 7) << 3;                 // lane-constant read swizzle (shorts)

  for (int T = 0; T < nk; ++T) {
    // ---- stage tile T (builtin: compiler tracks + waits before barrier) ----
    #pragma unroll
    for (int i = 0; i < 4; ++i)
      gload_lds16(pA + (size_t)T * 64 + i * l32, &As[i * 2048 + w * 512]);
    #pragma unroll
    for (int i = 0; i < 4; ++i)
      gload_lds16(pB + (size_t)T * 64 + i * l32, &Bs[i * 2048 + w * 512]);
    __syncthreads();

    // ---- compute tile T ----
    short8 af[4][2], bfv[4][2];
    #pragma unroll
    for (int m = 0; m < 4; ++m) {
      int ar = wm * 64 + m * 16 + lr;
      af[m][0] = *(const short8*)&As[ar * 64 + ((lg * 8) ^ rsw)];
      af[m][1] = *(const short8*)&As[ar * 64 + ((32 + lg * 8) ^ rsw)];
    }
    #pragma unroll
    for (int n = 0; n < 4; ++n) {
      int br = wn * 64 + n * 16 + lr;
      bfv[n][0] = *(const short8*)&Bs[br * 64 + ((lg * 8) ^ rsw)];
      bfv[n][1] = *(const short8*)&Bs[br * 64 + ((32 + lg * 8) ^ rsw)];
    }
    #pragma unroll
    for (int m = 0; m < 4; ++m)
      #pragma unroll
      for (int n = 0; n < 4; ++n) {
        acc[m][n] = MF(af[m][0], bfv[n][0], acc[m][n]);
        acc[m][n] = MF(af[m][1], bfv[n][1], acc[m][n]);
      }
    if (T + 1 < nk) __syncthreads();   // all reads done before next stage overwrites
  }

  // ---- epilogue ----
  short* Cs = (short*)Cv;
  if (SPLIT) Cs += (size_t)ks * ((size_t)M * N);
  #pragma unroll
  for (int m = 0; m < 4; ++m)
    #pragma unroll
    for (int n = 0; n < 4; ++n)
      #pragma unroll
      for (int rr = 0; rr < 4; ++rr) {
        int row = m0 + wm * 64 + m * 16 + lg * 4 + rr;
        int col = n0 + wn * 64 + n * 16 + lr;
        size_t idx = (size_t)row * N + col;
        float vv = acc[m][n][rr];
        if (EPI == 0) {
          Cs[idx] = f2bf(vv);
        } else if (EPI == 1) {
          float gl = 0.5f * vv * (1.0f + erff(vv * 0.70710678118654752f));
          ((short*)Cv)[idx] = f2bf(gl);
        } else {
          ((float*)Cv)[idx] = vv + resid[idx];
        }
      }
}

// ---------------- V transpose: qkv[.., v cols] -> vt[b][h][d][s] ----------------
__global__ __launch_bounds__(256) void vtrans(const short* __restrict__ QKV,
                                              short* __restrict__ VT) {
  const int st = blockIdx.x;   // s tile of 64
  const int bh = blockIdx.y;
  const int b = bh >> 4, h = bh & 15;
  const int t = threadIdx.x;
  __shared__ __align__(16) short T[64 * 128];
  const short* Vsrc = QKV + ((size_t)b * SEQ) * 6144 + 2 * D_MODEL + h * DK;
  {
    int r = t >> 4, c = (t & 15) * 8;
    #pragma unroll
    for (int i = 0; i < 4; ++i) {
      int rr = r + 16 * i;
      uint4 vv = *(const uint4*)(Vsrc + (size_t)(st * 64 + rr) * 6144 + c);
      *(uint4*)&T[rr * 128 + (c ^ (((rr >> 3) & 7) << 3))] = vv;
    }
  }
  __syncthreads();
  short* dst = VT + ((size_t)bh * DK) * SEQ + st * 64;
  {
    int c2 = (t & 7) * 8;
    #pragma unroll
    for (int i = 0; i < 4; ++i) {
      int d = (t >> 3) + 32 * i;
      short8 ov;
      #pragma unroll
      for (int j = 0; j < 8; ++j)
        ov[j] = T[(c2 + j) * 128 + (d ^ ((((c2 + j) >> 3) & 7) << 3))];
      *(short8*)(dst + (size_t)d * SEQ + c2) = ov;
    }
  }
}

// ---------------- Flash attention v3 (round-4 verified) ----------------
__global__ __launch_bounds__(512, 2) void attn3(const short* __restrict__ QKV,
                                                const short* __restrict__ VT,
                                                short* __restrict__ O) {
  const float SC = 0.12751743f;   // (1/sqrt(128)) * log2(e)
  const int a = blockIdx.x, bh = blockIdx.y;
  const int b = bh >> 4, h = bh & 15;
  const int t = threadIdx.x, w = t >> 6, lane = t & 63, lr = lane & 15, lg = lane >> 4;
  const short* Qp = QKV + ((size_t)b * SEQ) * 6144 + h * DK;
  const short* Kp = Qp + D_MODEL;
  const short* Vp = VT + ((size_t)bh * DK) * SEQ;   // [d][s]
  __shared__ __align__(16) short Ks[2][64 * 128];
  __shared__ __align__(16) short Vs[2][128 * 64];
  __shared__ __align__(16) short Ps[8][16][72];

  const int krr = t >> 4, kcc = (t & 15) * 8;
  const int vdd = t >> 3, vcc = (t & 7) * 8;
  const f32x4 z4 = {0.f, 0.f, 0.f, 0.f};

  for (int sub = 0; sub < 2; ++sub) {
    const int ts = sub ? (15 - a) : a;
    const int nt = 2 * ts + 2;
    const int qrow0 = ts * 128 + w * 16;

    short8 qf[4];
    #pragma unroll
    for (int ki = 0; ki < 4; ++ki)
      qf[ki] = *(const short8*)(Qp + (size_t)(qrow0 + lr) * 6144 + ki * 32 + lg * 8);

    f32x4 acc[8];
    #pragma unroll
    for (int nd = 0; nd < 8; ++nd) acc[nd] = z4;
    float mrow[4], lsum[4];
    #pragma unroll
    for (int r = 0; r < 4; ++r) { mrow[r] = -INFINITY; lsum[r] = 0.f; }

    uint4 krg[2], vrg[2];
    #pragma unroll
    for (int i = 0; i < 2; ++i) {
      krg[i] = *(const uint4*)(Kp + (size_t)(krr + 32 * i) * 6144 + kcc);
      vrg[i] = *(const uint4*)(Vp + (size_t)(vdd + 64 * i) * SEQ + vcc);
    }
    __syncthreads();
    #pragma unroll
    for (int i = 0; i < 2; ++i) {
      int r = krr + 32 * i;
      *(uint4*)&Ks[0][(r * 128 + kcc) ^ ((r & 7) << 3)] = krg[i];
      int d = vdd + 64 * i;
      *(uint4*)&Vs[0][(d * 64 + vcc) ^ ((d & 7) << 3)] = vrg[i];
    }
    __syncthreads();

    int cur = 0;
    for (int tt = 0; tt < nt; ++tt) {
      const bool pre = (tt + 1 < nt);
      if (pre) {
        #pragma unroll
        for (int i = 0; i < 2; ++i) {
          krg[i] = *(const uint4*)(Kp + (size_t)((tt + 1) * 64 + krr + 32 * i) * 6144 + kcc);
          vrg[i] = *(const uint4*)(Vp + (size_t)(vdd + 64 * i) * SEQ + (tt + 1) * 64 + vcc);
        }
      }

      f32x4 sf[4] = {z4, z4, z4, z4};
      #pragma unroll
      for (int ki = 0; ki < 4; ++ki) {
        #pragma unroll
        for (int nk = 0; nk < 4; ++nk) {
          int rr = nk * 16 + lr;
          short8 kf = *(const short8*)&Ks[cur][(rr * 128 + ki * 32 + lg * 8) ^ ((rr & 7) << 3)];
          sf[nk] = MF(qf[ki], kf, sf[nk]);
        }
      }

      const bool diag = (tt * 64 + 63 > qrow0);
      #pragma unroll
      for (int r = 0; r < 4; ++r) {
        int qg = qrow0 + lg * 4 + r;
        float s0 = sf[0][r] * SC, s1 = sf[1][r] * SC, s2 = sf[2][r] * SC, s3 = sf[3][r] * SC;
        if (diag) {
          int c0 = tt * 64 + lr;
          s0 = (c0      <= qg) ? s0 : -3.0e38f;
          s1 = (c0 + 16 <= qg) ? s1 : -3.0e38f;
          s2 = (c0 + 32 <= qg) ? s2 : -3.0e38f;
          s3 = (c0 + 48 <= qg) ? s3 : -3.0e38f;
        }
        float mx = fmaxf(fmaxf(s0, s1), fmaxf(s2, s3));
        mx = fmaxf(mx, __shfl_xor(mx, 1));
        mx = fmaxf(mx, __shfl_xor(mx, 2));
        mx = fmaxf(mx, __shfl_xor(mx, 4));
        mx = fmaxf(mx, __shfl_xor(mx, 8));
        float mnew = fmaxf(mrow[r], mx);
        float alpha = exp2f(mrow[r] - mnew);
        mrow[r] = mnew;
        float p0 = exp2f(s0 - mnew), p1 = exp2f(s1 - mnew),
              p2 = exp2f(s2 - mnew), p3 = exp2f(s3 - mnew);
        lsum[r] = lsum[r] * alpha + ((p0 + p1) + (p2 + p3));
        #pragma unroll
        for (int nd = 0; nd < 8; ++nd) acc[nd][r] *= alpha;
        short* pr = &Ps[w][lg * 4 + r][0];
        pr[lr]      = f2bf(p0);
        pr[16 + lr] = f2bf(p1);
        pr[32 + lr] = f2bf(p2);
        pr[48 + lr] = f2bf(p3);
      }
      asm volatile("s_waitcnt lgkmcnt(0)" ::: "memory");
      __builtin_amdgcn_sched_barrier(0);

      short8 pf0 = *(const short8*)&Ps[w][lr][lg * 8];
      short8 pf1 = *(const short8*)&Ps[w][lr][32 + lg * 8];
      #pragma unroll
      for (int nd = 0; nd < 8; ++nd) {
        int rr = nd * 16 + lr;
        short8 vf0 = *(const short8*)&Vs[cur][(rr * 64 + lg * 8) ^ ((rr & 7) << 3)];
        short8 vf1 = *(const short8*)&Vs[cur][(rr * 64 + 32 + lg * 8) ^ ((rr & 7) << 3)];
        acc[nd] = MF(pf0, vf0, acc[nd]);
        acc[nd] = MF(pf1, vf1, acc[nd]);
      }
      __syncthreads();
      if (pre) {
        #pragma unroll
        for (int i = 0; i < 2; ++i) {
          int r = krr + 32 * i;
          *(uint4*)&Ks[cur ^ 1][(r * 128 + kcc) ^ ((r & 7) << 3)] = krg[i];
          int d = vdd + 64 * i;
          *(uint4*)&Vs[cur ^ 1][(d * 64 + vcc) ^ ((d & 7) << 3)] = vrg[i];
        }
      }
      __syncthreads();
      cur ^= 1;
    }

    float inv[4];
    #pragma unroll
    for (int r = 0; r < 4; ++r) {
      float ls = lsum[r];
      ls += __shfl_xor(ls, 1);
      ls += __shfl_xor(ls, 2);
      ls += __shfl_xor(ls, 4);
      ls += __shfl_xor(ls, 8);
      inv[r] = 1.0f / ls;
    }
    #pragma unroll
    for (int nd = 0; nd < 8; ++nd)
      #pragma unroll
      for (int r = 0; r < 4; ++r) {
        int row = qrow0 + lg * 4 + r;
        O[(size_t)(b * SEQ + row) * D_MODEL + h * DK + nd * 16 + lr] = f2bf(acc[nd][r] * inv[r]);
      }
  }
}

// ======== FALLBACK PATH (round-2 verified kernels) ========
template<int EPI>
__global__ __launch_bounds__(256) void gemm_bt(const short* __restrict__ A,
                                               const float* __restrict__ B,
                                               void* Cv,
                                               const float* resid,
                                               int M, int N, int K) {
  __shared__ __align__(16) short As[128][72];
  __shared__ __align__(16) short Bs[128][72];
  const int t = threadIdx.x;
  const int m0 = blockIdx.x * 128, n0 = blockIdx.y * 128;
  const int wave = t >> 6, lane = t & 63, lr = lane & 15, lg = lane >> 4;
  const int wr = (wave >> 1) * 64, wc = (wave & 1) * 64;

  f32x4 acc[4][4];
  const f32x4 z4 = {0.f, 0.f, 0.f, 0.f};
  #pragma unroll
  for (int m = 0; m < 4; ++m)
    #pragma unroll
    for (int n = 0; n < 4; ++n) acc[m][n] = z4;

  int ar[4], ac[4];
  #pragma unroll
  for (int i = 0; i < 4; ++i) { int u = t + 256*i; ar[i] = u >> 3; ac[i] = (u & 7) * 8; }

  for (int k0 = 0; k0 < K; k0 += 64) {
    #pragma unroll
    for (int i = 0; i < 4; ++i) {
      uint4 va = *(const uint4*)(A + (size_t)(m0 + ar[i]) * K + k0 + ac[i]);
      *(uint4*)&As[ar[i]][ac[i]] = va;
    }
    #pragma unroll
    for (int i = 0; i < 4; ++i) {
      const float4* bp = (const float4*)(B + (size_t)(n0 + ar[i]) * K + k0 + ac[i]);
      float4 b0 = bp[0], b1 = bp[1];
      short8 pb = { f2bf(b0.x), f2bf(b0.y), f2bf(b0.z), f2bf(b0.w),
                    f2bf(b1.x), f2bf(b1.y), f2bf(b1.z), f2bf(b1.w) };
      *(short8*)&Bs[ar[i]][ac[i]] = pb;
    }
    __syncthreads();
    #pragma unroll
    for (int kk = 0; kk < 64; kk += 32) {
      short8 af[4], bfr[4];
      #pragma unroll
      for (int m = 0; m < 4; ++m) af[m]  = *(const short8*)&As[wr + m*16 + lr][kk + lg*8];
      #pragma unroll
      for (int n = 0; n < 4; ++n) bfr[n] = *(const short8*)&Bs[wc + n*16 + lr][kk + lg*8];
      #pragma unroll
      for (int m = 0; m < 4; ++m)
        #pragma unroll
        for (int n = 0; n < 4; ++n)
          acc[m][n] = MF(af[m], bfr[n], acc[m][n]);
    }
    __syncthreads();
  }

  #pragma unroll
  for (int m = 0; m < 4; ++m)
    #pragma unroll
    for (int n = 0; n < 4; ++n)
      #pragma unroll
      for (int r = 0; r < 4; ++r) {
        int row = m0 + wr + m*16 + lg*4 + r;
        int col = n0 + wc + n*16 + lr;
        size_t idx = (size_t)row * N + col;
        float vv = acc[m][n][r];
        if (EPI == 0) {
          ((short*)Cv)[idx] = f2bf(vv);
        } else if (EPI == 1) {
          float gl = 0.5f * vv * (1.0f + erff(vv * 0.70710678118654752f));
          ((short*)Cv)[idx] = f2bf(gl);
        } else {
          ((float*)Cv)[idx] = vv + resid[idx];
        }
      }
}

__global__ __launch_bounds__(256) void attn_k(const short* __restrict__ Q,
                                              const short* __restrict__ K,
                                              const short* __restrict__ V,
                                              short* __restrict__ O) {
  const float scale = 0.08838834764831845f;
  const int qt = blockIdx.x;
  const int bh = blockIdx.y;
  const int b = bh >> 4, h = bh & 15;
  const size_t base = ((size_t)b * SEQ) * D_MODEL + (size_t)h * DK;
  const int t = threadIdx.x, wave = t >> 6, lane = t & 63, lr = lane & 15, lg = lane >> 4;

  __shared__ __align__(16) short Ks[32][136];
  __shared__ __align__(16) short Vt[128][40];
  __shared__ __align__(16) short Ps[4][32][40];

  const int qrow0 = qt * 128 + wave * 32;
  short8 qf[2][4];
  #pragma unroll
  for (int mq = 0; mq < 2; ++mq)
    #pragma unroll
    for (int ki = 0; ki < 4; ++ki)
      qf[mq][ki] = *(const short8*)(Q + base + (size_t)(qrow0 + mq*16 + lr) * D_MODEL + ki*32 + lg*8);

  f32x4 acc[2][8];
  const f32x4 z4 = {0.f, 0.f, 0.f, 0.f};
  #pragma unroll
  for (int mq = 0; mq < 2; ++mq)
    #pragma unroll
    for (int nd = 0; nd < 8; ++nd) acc[mq][nd] = z4;
  float mrow[2][4], lsum[2][4];
  #pragma unroll
  for (int mq = 0; mq < 2; ++mq)
    #pragma unroll
    for (int r = 0; r < 4; ++r) { mrow[mq][r] = -INFINITY; lsum[mq][r] = 0.f; }

  const int lastt = qt * 4 + 3;
  for (int tt = 0; tt <= lastt; ++tt) {
    #pragma unroll
    for (int i = 0; i < 2; ++i) {
      int u = t + 256*i; int r = u >> 4; int c = (u & 15) * 8;
      *(uint4*)&Ks[r][c] = *(const uint4*)(K + base + (size_t)(tt*32 + r) * D_MODEL + c);
      uint4 vv = *(const uint4*)(V + base + (size_t)(tt*32 + r) * D_MODEL + c);
      const short* sv = (const short*)&vv;
      #pragma unroll
      for (int j = 0; j < 8; ++j) Vt[c + j][r] = sv[j];
    }
    __syncthreads();
    if (tt <= qt * 4 + wave) {
      f32x4 sf[2][2] = {{z4, z4}, {z4, z4}};
      #pragma unroll
      for (int ki = 0; ki < 4; ++ki) {
        short8 kf0 = *(const short8*)&Ks[lr][ki*32 + lg*8];
        short8 kf1 = *(const short8*)&Ks[16 + lr][ki*32 + lg*8];
        sf[0][0] = MF(qf[0][ki], kf0, sf[0][0]);
        sf[0][1] = MF(qf[0][ki], kf1, sf[0][1]);
        sf[1][0] = MF(qf[1][ki], kf0, sf[1][0]);
        sf[1][1] = MF(qf[1][ki], kf1, sf[1][1]);
      }
      #pragma unroll
      for (int mq = 0; mq < 2; ++mq) {
        #pragma unroll
        for (int r = 0; r < 4; ++r) {
          int qg = qrow0 + mq*16 + lg*4 + r;
          float s0 = sf[mq][0][r] * scale;
          float s1 = sf[mq][1][r] * scale;
          if (tt*32 + lr > qg)       s0 = -INFINITY;
          if (tt*32 + 16 + lr > qg)  s1 = -INFINITY;
          float mx = fmaxf(s0, s1);
          mx = fmaxf(mx, __shfl_xor(mx, 1));
          mx = fmaxf(mx, __shfl_xor(mx, 2));
          mx = fmaxf(mx, __shfl_xor(mx, 4));
          mx = fmaxf(mx, __shfl_xor(mx, 8));
          float mnew = fmaxf(mrow[mq][r], mx);
          float alpha = __expf(mrow[mq][r] - mnew);
          mrow[mq][r] = mnew;
          float p0 = __expf(s0 - mnew);
          float p1 = __expf(s1 - mnew);
          float ps = p0 + p1;
          ps += __shfl_xor(ps, 1);
          ps += __shfl_xor(ps, 2);
          ps += __shfl_xor(ps, 4);
          ps += __shfl_xor(ps, 8);
          lsum[mq][r] = lsum[mq][r] * alpha + ps;
          #pragma unroll
          for (int nd = 0; nd < 8; ++nd) acc[mq][nd][r] *= alpha;
          Ps[wave][mq*16 + lg*4 + r][lr]      = f2bf(p0);
          Ps[wave][mq*16 + lg*4 + r][16 + lr] = f2bf(p1);
        }
      }
      asm volatile("s_waitcnt lgkmcnt(0)" ::: "memory");
      short8 pf0 = *(const short8*)&Ps[wave][lr][lg*8];
      short8 pf1 = *(const short8*)&Ps[wave][16 + lr][lg*8];
      #pragma unroll
      for (int nd = 0; nd < 8; ++nd) {
        short8 vf = *(const short8*)&Vt[nd*16 + lr][lg*8];
        acc[0][nd] = MF(pf0, vf, acc[0][nd]);
        acc[1][nd] = MF(pf1, vf, acc[1][nd]);
      }
    }
    __syncthreads();
  }

  #pragma unroll
  for (int mq = 0; mq < 2; ++mq)
    #pragma unroll
    for (int nd = 0; nd < 8; ++nd)
      #pragma unroll
      for (int r = 0; r < 4; ++r) {
        int row = qrow0 + mq*16 + lg*4 + r;
        O[base + (size_t)row * D_MODEL + nd*16 + lr] = f2bf(acc[mq][nd][r] / lsum[mq][r]);
      }
}

// ---------------- launch ----------------
extern "C" void kernel_launch(void* const* d_in, const int* in_sizes, int n_in,
                              void* d_out, int out_size, void* d_ws, size_t ws_size,
                              hipStream_t stream) {
  const float* x  = (const float*)d_in[0];
  const float* wq = (const float*)d_in[1];
  const float* wk = (const float*)d_in[2];
  const float* wv = (const float*)d_in[3];
  const float* wo = (const float*)d_in[4];
  const float* w1 = (const float*)d_in[5];
  const float* w2 = (const float*)d_in[6];
  const float* g1 = (const float*)d_in[7];
  const float* g2 = (const float*)d_in[8];
  float* out = (float*)d_out;
  char* ws = (char*)d_ws;

  const size_t NEED = (size_t)192 << 20;
  if (ws_size >= NEED) {
    // fast path layout (192 MiB):
    //   [0,24M) wqkv | [24,32M) wo | [32,64M) w1 | [64,96M) w2   (bf16 weights)
    //   [96,144M) qkv | [144,160M) vt | [160,176M) ab | [176,192M) xn
    //   oproj phase: partials (2x16M bf16) at [96,128)   (qkv/vt dead)
    //   FFN phase:   hb = [96,160M); FFN2 partials (2x16M bf16) at [160,192) (ab/xn dead)
    short* wqkv = (short*)(ws);
    short* wo_b = (short*)(ws + ((size_t)24 << 20));
    short* w1_b = (short*)(ws + ((size_t)32 << 20));
    short* w2_b = (short*)(ws + ((size_t)64 << 20));
    short* qkv  = (short*)(ws + ((size_t)96 << 20));
    short* vt   = (short*)(ws + ((size_t)144 << 20));
    short* ab   = (short*)(ws + ((size_t)160 << 20));
    short* xn   = (short*)(ws + ((size_t)176 << 20));
    short* hb   = (short*)(ws + ((size_t)96 << 20));
    short* po   = (short*)(ws + ((size_t)96 << 20));    // oproj partials (2x MROWSxD bf16)
    short* pf   = (short*)(ws + ((size_t)160 << 20));   // FFN2 partials (2x MROWSxD bf16)

    const int NW = D_MODEL * D_MODEL / 8;
    f2b_k<<<(NW + 255) / 256, 256, 0, stream>>>(wq, wqkv,                   NW);
    f2b_k<<<(NW + 255) / 256, 256, 0, stream>>>(wk, wqkv + (size_t)D_MODEL * D_MODEL,     NW);
    f2b_k<<<(NW + 255) / 256, 256, 0, stream>>>(wv, wqkv + (size_t)2 * D_MODEL * D_MODEL, NW);
    f2b_k<<<(NW + 255) / 256, 256, 0, stream>>>(wo, wo_b, NW);
    const int NF = DFF * D_MODEL / 8;
    f2b_k<<<(NF + 255) / 256, 256, 0, stream>>>(w1, w1_b, NF);
    f2b_k<<<(NF + 255) / 256, 256, 0, stream>>>(w2, w2_b, NF);

    const int N8 = MROWS * D_MODEL / 8;

    rmsnorm_k<<<MROWS, 256, 0, stream>>>(x, g1, xn);
    // QKV: 32x48 = 1536 blocks
    gemm128s<0,0><<<dim3(32 * 48), 256, 0, stream>>>(xn, wqkv, qkv, nullptr,
                                                     MROWS, 6144, D_MODEL, D_MODEL, 32);
    vtrans<<<dim3(SEQ/64, BATCH*NHEAD), 256, 0, stream>>>(qkv, vt);
    attn3<<<dim3(8, BATCH*NHEAD), 512, 0, stream>>>(qkv, vt, ab);
    // o-proj: split-K x2 -> 32x16x2 = 1024 blocks, bf16 partials; combine with resid x
    gemm128s<0,1><<<dim3(32 * 16 * 2), 256, 0, stream>>>(ab, wo_b, po, nullptr,
                                                         MROWS, D_MODEL, D_MODEL / 2, D_MODEL, 32);
    combine_bb<<<(N8 + 255) / 256, 256, 0, stream>>>(po, po + (size_t)MROWS * D_MODEL, x, out, N8);
    rmsnorm_k<<<MROWS, 256, 0, stream>>>(out, g2, xn);
    // FFN1: 32x64 = 2048 blocks, GELU
    gemm128s<1,0><<<dim3(32 * 64), 256, 0, stream>>>(xn, w1_b, hb, nullptr,
                                                     MROWS, DFF, D_MODEL, D_MODEL, 32);
    // FFN2: split-K x2 -> 1024 blocks, bf16 partials; combine in-place with resid out
    gemm128s<0,1><<<dim3(32 * 16 * 2), 256, 0, stream>>>(hb, w2_b, pf, nullptr,
                                                         MROWS, D_MODEL, DFF / 2, DFF, 32);
    combine_bb<<<(N8 + 255) / 256, 256, 0, stream>>>(pf, pf + (size_t)MROWS * D_MODEL, out, out, N8);
  } else {
    // fallback: round-2 verified path (80 MiB)
    short* qb = (short*)(ws + ((size_t)0  << 20));
    short* kb = (short*)(ws + ((size_t)16 << 20));
    short* vb = (short*)(ws + ((size_t)32 << 20));
    short* ab = (short*)(ws + ((size_t)48 << 20));
    short* xn = (short*)(ws + ((size_t)64 << 20));
    short* hb = (short*)(ws + ((size_t)0  << 20));

    dim3 gproj(MROWS / 128, D_MODEL / 128);
    rmsnorm_k<<<MROWS, 256, 0, stream>>>(x, g1, xn);
    gemm_bt<0><<<gproj, 256, 0, stream>>>(xn, wq, qb, nullptr, MROWS, D_MODEL, D_MODEL);
    gemm_bt<0><<<gproj, 256, 0, stream>>>(xn, wk, kb, nullptr, MROWS, D_MODEL, D_MODEL);
    gemm_bt<0><<<gproj, 256, 0, stream>>>(xn, wv, vb, nullptr, MROWS, D_MODEL, D_MODEL);
    attn_k<<<dim3(SEQ / 128, BATCH * NHEAD), 256, 0, stream>>>(qb, kb, vb, ab);
    gemm_bt<2><<<gproj, 256, 0, stream>>>(ab, wo, out, x, MROWS, D_MODEL, D_MODEL);
    rmsnorm_k<<<MROWS, 256, 0, stream>>>(out, g2, xn);
    for (int half = 0; half < 2; ++half) {
      const short* xh = xn  + (size_t)half * 2048 * D_MODEL;
      float*       oh = out + (size_t)half * 2048 * D_MODEL;
      gemm_bt<1><<<dim3(2048 / 128, DFF / 128), 256, 0, stream>>>(xh, w1, hb, nullptr, 2048, DFF, D_MODEL);
      gemm_bt<2><<<dim3(2048 / 128, D_MODEL / 128), 256, 0, stream>>>(hb, w2, oh, oh, 2048, D_MODEL, DFF);
    }
  }
}